// Round 8
// baseline (237.062 us; speedup 1.0000x reference)
//
#include <hip/hip_runtime.h>
#include <math.h>

// InfiniAttention fused forward, MI355X round 8.
// B=4, N=2048, DIM=64, H=8, DH=64.
// Round-8: k_flash = round-6 structure (128-row blocks, 4 waves, 2 strips/wave
// = best LDS economics) + global_load_lds(16B) DMA staging, double-buffered
// tiles, raw s_barrier + s_waitcnt vmcnt(4) (never drains mid-loop). DMA
// forces pitch-64 LDS rows -> kb/vbT are stored GLOBALLY with a 16B-block
// xor-swizzle (block j at j^(row&7)); frag reads unswizzle in the index
// (2-way conflicts = free). k_gv reads vbT with the matching unswizzle.
// k_memacc / k_reduce / k_outproj / tight kh path byte-identical to round-6.
//
// Workspace (floats, 16908288 total = 67,633,152 B):
//   kh   @ 0         f32  4194304
//   qb   @ 4194304   bf16 [bh][n][d]
//   kb   @ 6291456   bf16 [bh][n][d]   (block-swizzled)
//   vb   @ 8388608   bf16 [bh][n][d]
//   vbT  @ 10485760  bf16 [bh][e][n]   (block-swizzled)
//   Gv   @ 12582912  f32  131072  [bh][d][e]
//   pm   @ 12713984  f32  2097152 (16 chunks)  <- o bf16 aliases pm
//   pg   @ 14811136  f32  2097152

#define B_   4
#define N_   2048
#define H_   8
#define BH_  32
#define KP   72      // bf16 LDS pitch for non-DMA tiles (144 B)

typedef __bf16 bf16x8 __attribute__((ext_vector_type(8)));
typedef __bf16 bf16x4 __attribute__((ext_vector_type(4)));
typedef float  f32x4  __attribute__((ext_vector_type(4)));

__device__ __forceinline__ float eluf(float x) {
    return x > 0.0f ? x : expm1f(x);   // expm1 critical near 0
}

__device__ __forceinline__ void gl2lds16(const void* g, void* l) {
    // async global->LDS DMA, 16 B/lane; LDS dest = uniform base + lane*16
    __builtin_amdgcn_global_load_lds(
        (const __attribute__((address_space(1))) unsigned int*)g,
        (__attribute__((address_space(3))) unsigned int*)l, 16, 0, 0);
}

// ---------------- K2: head projections -----------------
// Sequential f32 FMA chain (k-path bit-matched to np sgemm; q/v loose).
// kb and vbT stored with 16B-block swizzle: block j at j^(row&7).
__global__ __launch_bounds__(256) void k_proj(
    const float* __restrict__ q, const float* __restrict__ k, const float* __restrict__ v,
    const float* __restrict__ Wq, const float* __restrict__ Wk, const float* __restrict__ Wv,
    __bf16* __restrict__ qb, float* __restrict__ kh, __bf16* __restrict__ kb,
    __bf16* __restrict__ vb, __bf16* __restrict__ vbT)
{
    const int which = blockIdx.z;
    const float* __restrict__ src = (which == 0) ? q : (which == 1) ? k : v;
    const float* __restrict__ W   = (which == 0) ? Wq : (which == 1) ? Wk : Wv;
    const int h    = blockIdx.y;
    const int row0 = blockIdx.x * 64;   // over B*N = 8192

    __shared__ __align__(16) float AsT[64][68];   // [dim][row]
    __shared__ __align__(16) float WsT[64][68];   // [dim][col]; reused for v^T
    const int tid = threadIdx.x;
    for (int s = 0; s < 16; ++s) {
        int flat = s * 256 + tid;
        int r = flat >> 6, d = flat & 63;
        AsT[d][r] = src[(size_t)(row0 + r) * 64 + d];
        WsT[d][r] = W[(size_t)(h * 64 + r) * 64 + d];
    }
    __syncthreads();

    const int ty = tid >> 4, tx = tid & 15;
    float acc[4][4];
    #pragma unroll
    for (int i = 0; i < 4; ++i)
        #pragma unroll
        for (int j = 0; j < 4; ++j) acc[i][j] = 0.0f;
    for (int kd = 0; kd < 64; ++kd) {
        float4 a4 = *(const float4*)&AsT[kd][ty * 4];
        float4 w4 = *(const float4*)&WsT[kd][tx * 4];
        float a[4] = {a4.x, a4.y, a4.z, a4.w};
        float w[4] = {w4.x, w4.y, w4.z, w4.w};
        #pragma unroll
        for (int i = 0; i < 4; ++i)
            #pragma unroll
            for (int j = 0; j < 4; ++j) acc[i][j] = fmaf(a[i], w[j], acc[i][j]);
    }

    const int b = row0 >> 11, nb = row0 & 2047;
    if (which == 0) {
        #pragma unroll
        for (int i = 0; i < 4; ++i) {
            size_t idx = ((((size_t)b * H_ + h) * N_ + nb + ty * 4 + i) << 6) + tx * 4;
            bf16x4 o4 = {(__bf16)acc[i][0], (__bf16)acc[i][1],
                         (__bf16)acc[i][2], (__bf16)acc[i][3]};
            *(bf16x4*)&qb[idx] = o4;
        }
    } else if (which == 1) {
        #pragma unroll
        for (int i = 0; i < 4; ++i) {
            size_t rowbase = (((size_t)b * H_ + h) * N_ + nb + ty * 4 + i) << 6;
            *(float4*)&kh[rowbase + tx * 4] =
                make_float4(acc[i][0], acc[i][1], acc[i][2], acc[i][3]);
            bf16x4 o4 = {(__bf16)acc[i][0], (__bf16)acc[i][1],
                         (__bf16)acc[i][2], (__bf16)acc[i][3]};
            const int s = (ty * 4 + i) & 7;   // row&7 (nb multiple of 64)
            *(bf16x4*)&kb[rowbase + (((tx >> 1) ^ s) << 3) + (tx & 1) * 4] = o4;
        }
    } else {
        #pragma unroll
        for (int i = 0; i < 4; ++i) {
            size_t idx = ((((size_t)b * H_ + h) * N_ + nb + ty * 4 + i) << 6) + tx * 4;
            bf16x4 o4 = {(__bf16)acc[i][0], (__bf16)acc[i][1],
                         (__bf16)acc[i][2], (__bf16)acc[i][3]};
            *(bf16x4*)&vb[idx] = o4;
        }
        __syncthreads();
        #pragma unroll
        for (int i = 0; i < 4; ++i)
            #pragma unroll
            for (int j = 0; j < 4; ++j) WsT[tx * 4 + j][ty * 4 + i] = acc[i][j];
        __syncthreads();
        const int e = tid >> 2, nc = (tid & 3) * 16;
        bf16x8 lo, hi;
        #pragma unroll
        for (int jj = 0; jj < 8; ++jj) {
            lo[jj] = (__bf16)WsT[e][nc + jj];
            hi[jj] = (__bf16)WsT[e][nc + 8 + jj];
        }
        size_t rowb = (((size_t)b * H_ + h) * 64 + e) * (size_t)N_ + nb;
        const int j0 = (nc >> 3) ^ (e & 7);
        const int j1 = ((nc >> 3) + 1) ^ (e & 7);
        *(bf16x8*)&vbT[rowb + j0 * 8] = lo;
        *(bf16x8*)&vbT[rowb + j1 * 8] = hi;
    }
}

// ---- K3: memory-update on split-bf16 MFMA (unchanged from round-6 PASS) ----
__global__ __launch_bounds__(256) void k_memacc(
    const float* __restrict__ kh, const __bf16* __restrict__ vb,
    const float* __restrict__ mem, const float* __restrict__ mem_norm,
    float* __restrict__ pmem, float* __restrict__ out_norm)
{
    const int chunk = blockIdx.x;    // 0..15
    const int bh    = blockIdx.y;
    const int h     = bh & 7;
    const int n0    = chunk * 128;

    __shared__ __align__(16) __bf16 memT_hi[64 * KP], memT_lo[64 * KP]; // [e][d]
    __shared__ __align__(16) __bf16 ekn_hi[64 * KP],  ekn_lo[64 * KP];  // [n][d]
    __shared__ __align__(16) __bf16 ekT_hi[64 * KP],  ekT_lo[64 * KP];  // [d][n]
    __shared__ __align__(16) __bf16 vtT_hi[64 * KP],  vtT_lo[64 * KP];  // [e][n]

    const int tid  = threadIdx.x;
    const int w    = tid >> 6, lane = tid & 63;
    const int quad = lane >> 4, m = lane & 15;

    for (int s = 0; s < 16; ++s) {
        int flat = s * 256 + tid;          // flat = d*64 + e
        int d = flat >> 6, e = flat & 63;
        float mv = mem[(size_t)h * 4096 + flat];
        __bf16 hi = (__bf16)mv;
        memT_hi[e * KP + d] = hi;
        memT_lo[e * KP + d] = (__bf16)(mv - (float)hi);
    }

    f32x4 accM[4];
    #pragma unroll
    for (int t = 0; t < 4; ++t) { f32x4 z = {0.f, 0.f, 0.f, 0.f}; accM[t] = z; }
    __syncthreads();

    for (int sub = 0; sub < 2; ++sub) {
        const int nb = n0 + sub * 64;
        for (int rr = w; rr < 64; rr += 4) {
            const int n = nb + rr;
            float ekv = eluf(kh[((size_t)bh * N_ + n) * 64 + lane]);
            __bf16 hi = (__bf16)ekv;
            __bf16 lo = (__bf16)(ekv - (float)hi);
            ekn_hi[rr * KP + lane] = hi;
            ekn_lo[rr * KP + lane] = lo;
            ekT_hi[lane * KP + rr] = hi;
            ekT_lo[lane * KP + rr] = lo;
            float srt = ekv;
            #pragma unroll
            for (int m2 = 32; m2; m2 >>= 1) srt += __shfl_xor(srt, m2, 64);
            if (lane == 0) out_norm[(size_t)bh * N_ + n] = srt;
        }
        __syncthreads();

        f32x4 km[4];
        #pragma unroll
        for (int t = 0; t < 4; ++t) { f32x4 z = {0.f, 0.f, 0.f, 0.f}; km[t] = z; }
        #pragma unroll
        for (int c2 = 0; c2 < 2; ++c2) {
            bf16x8 Ah = *(const bf16x8*)&ekn_hi[(w * 16 + m) * KP + c2 * 32 + quad * 8];
            bf16x8 Al = *(const bf16x8*)&ekn_lo[(w * 16 + m) * KP + c2 * 32 + quad * 8];
            #pragma unroll
            for (int et = 0; et < 4; ++et) {
                bf16x8 Bh = *(const bf16x8*)&memT_hi[(et * 16 + m) * KP + c2 * 32 + quad * 8];
                bf16x8 Bl = *(const bf16x8*)&memT_lo[(et * 16 + m) * KP + c2 * 32 + quad * 8];
                km[et] = __builtin_amdgcn_mfma_f32_16x16x32_bf16(Al, Bh, km[et], 0, 0, 0);
                km[et] = __builtin_amdgcn_mfma_f32_16x16x32_bf16(Ah, Bl, km[et], 0, 0, 0);
                km[et] = __builtin_amdgcn_mfma_f32_16x16x32_bf16(Ah, Bh, km[et], 0, 0, 0);
            }
        }
        float nrmv[4];
        #pragma unroll
        for (int r = 0; r < 4; ++r)
            nrmv[r] = mem_norm[(size_t)h * N_ + nb + w * 16 + quad * 4 + r];
        #pragma unroll
        for (int et = 0; et < 4; ++et) {
            #pragma unroll
            for (int r = 0; r < 4; ++r) {
                const int nl = w * 16 + quad * 4 + r;
                const int e  = et * 16 + m;
                float vh  = (float)vb[((size_t)bh * N_ + nb + nl) * 64 + e];
                float ekv = (float)ekn_hi[nl * KP + e] + (float)ekn_lo[nl * KP + e];
                float vt  = vh - km[et][r] / (ekv * nrmv[r]);
                __bf16 hi = (__bf16)vt;
                vtT_hi[e * KP + nl] = hi;
                vtT_lo[e * KP + nl] = (__bf16)(vt - (float)hi);
            }
        }
        __syncthreads();

        #pragma unroll
        for (int c2 = 0; c2 < 2; ++c2) {
            bf16x8 Ah = *(const bf16x8*)&ekT_hi[(w * 16 + m) * KP + c2 * 32 + quad * 8];
            bf16x8 Al = *(const bf16x8*)&ekT_lo[(w * 16 + m) * KP + c2 * 32 + quad * 8];
            #pragma unroll
            for (int et = 0; et < 4; ++et) {
                bf16x8 Bh = *(const bf16x8*)&vtT_hi[(et * 16 + m) * KP + c2 * 32 + quad * 8];
                bf16x8 Bl = *(const bf16x8*)&vtT_lo[(et * 16 + m) * KP + c2 * 32 + quad * 8];
                accM[et] = __builtin_amdgcn_mfma_f32_16x16x32_bf16(Al, Bh, accM[et], 0, 0, 0);
                accM[et] = __builtin_amdgcn_mfma_f32_16x16x32_bf16(Ah, Bl, accM[et], 0, 0, 0);
                accM[et] = __builtin_amdgcn_mfma_f32_16x16x32_bf16(Ah, Bh, accM[et], 0, 0, 0);
            }
        }
        __syncthreads();
    }

    const size_t base = ((size_t)chunk * BH_ + bh) * 4096;
    #pragma unroll
    for (int et = 0; et < 4; ++et)
        #pragma unroll
        for (int r = 0; r < 4; ++r)
            pmem[base + (size_t)(w * 16 + quad * 4 + r) * 64 + et * 16 + m] =
                accM[et][r];
}

// ---- K3g: Gv partials = Wg^T @ vh (vbT read with un-swizzle) ----
__global__ __launch_bounds__(256) void k_gv(
    const float* __restrict__ Wg, const __bf16* __restrict__ vbT,
    float* __restrict__ pGv)
{
    const int chunk = blockIdx.x;    // 0..15
    const int bh    = blockIdx.y;
    const int n0    = chunk * 128;
    __shared__ __align__(16) __bf16 WgT[64 * 136];   // [d][n], pitch 272B
    const int tid  = threadIdx.x;
    const int w    = tid >> 6, lane = tid & 63;
    const int quad = lane >> 4, m = tid & 15;

    for (int s = 0; s < 8; ++s) {
        int f4 = s * 256 + tid;
        int n = f4 >> 4, dg = (f4 & 15) * 4;
        float4 wv = *(const float4*)&Wg[(size_t)(n0 + n) * 64 + dg];
        WgT[(dg + 0) * 136 + n] = (__bf16)wv.x;
        WgT[(dg + 1) * 136 + n] = (__bf16)wv.y;
        WgT[(dg + 2) * 136 + n] = (__bf16)wv.z;
        WgT[(dg + 3) * 136 + n] = (__bf16)wv.w;
    }
    __syncthreads();

    f32x4 acc[4];
    #pragma unroll
    for (int t = 0; t < 4; ++t) { f32x4 z = {0.f, 0.f, 0.f, 0.f}; acc[t] = z; }
    #pragma unroll
    for (int c = 0; c < 4; ++c) {
        bf16x8 Af = *(const bf16x8*)&WgT[(w * 16 + m) * 136 + c * 32 + quad * 8];
        #pragma unroll
        for (int et = 0; et < 4; ++et) {
            // vbT is block-swizzled: window = 64 elems, block j at j^(e&7)
            const int jb = ((4 * c + quad) & 7) ^ (m & 7);
            bf16x8 Bf = *(const bf16x8*)&vbT[((size_t)bh * 64 + et * 16 + m) * N_ +
                                             n0 + (c >> 1) * 64 + jb * 8];
            acc[et] = __builtin_amdgcn_mfma_f32_16x16x32_bf16(Af, Bf, acc[et], 0, 0, 0);
        }
    }
    const size_t base = ((size_t)chunk * BH_ + bh) * 4096;
    #pragma unroll
    for (int et = 0; et < 4; ++et)
        #pragma unroll
        for (int r = 0; r < 4; ++r)
            pGv[base + (size_t)(w * 16 + quad * 4 + r) * 64 + et * 16 + m] =
                acc[et][r];
}

// ---------------- K3b: reduce partials (unchanged) ----------------
__global__ __launch_bounds__(256) void k_reduce(
    const float* __restrict__ mem, const float* __restrict__ pmem,
    const float* __restrict__ pGv, float* __restrict__ out_mem, float* __restrict__ Gv)
{
    const int idx = blockIdx.x * 256 + threadIdx.x;
    const int bh = idx >> 12, h = bh & 7, de = idx & 4095;
    float sm = mem[(size_t)h * 4096 + de];
    float sg = 0.0f;
    #pragma unroll
    for (int c = 0; c < 16; ++c) {
        sm += pmem[(size_t)c * 131072 + idx];
        sg += pGv[(size_t)c * 131072 + idx];
    }
    out_mem[idx] = sm;
    Gv[idx] = sg;
}

// ---------- K4: flash attention, DMA-staged double-buffered tiles ----------
// 256 thr = 4 waves; 128-row blocks; wave owns 32 q-rows (2 strips).
// Tiles staged via global_load_lds(16B) into pitch-64 LDS (layout forced:
// lane*16 linear) -- global kb/vbT are pre-swizzled so frag reads are 2-way.
// Raw s_barrier + s_waitcnt vmcnt(4): DMA of tile c+1 overlaps compute on c.
__global__ __launch_bounds__(256, 4) void k_flash(
    const __bf16* __restrict__ qb, const __bf16* __restrict__ kb,
    const __bf16* __restrict__ vbT, const float* __restrict__ mem,
    const float* __restrict__ mem_norm, const float* __restrict__ Gv,
    const float* __restrict__ s_local_p, const float* __restrict__ s_long_p,
    __bf16* __restrict__ o)
{
    const int n0 = blockIdx.x * 128;
    const int bh = blockIdx.y;
    const int h  = bh & 7;
    const __bf16* __restrict__ kbp = kb  + (size_t)bh * N_ * 64;
    const __bf16* __restrict__ vtp = vbT + (size_t)bh * 64 * N_;

    __shared__ __align__(16) __bf16 Kt[2][64 * 64];   // [kcol][d-blk swz], pitch 64
    __shared__ __align__(16) __bf16 Vt[2][64 * 64];   // [e][n-blk swz],   pitch 64
    __shared__ __align__(16) __bf16 Pw[128 * KP];     // [qrow][kcol] per-wave strips
    __shared__ float lsl[128];
    __shared__ float nrm_l[128];

    const int tid  = threadIdx.x;
    const int w    = tid >> 6, lane = tid & 63;
    const int quad = lane >> 4, m = lane & 15;
    const int sw   = m & 7;                 // read-side unswizzle key (row&7)
    const float gl   = 1.0f - 1.0f / (1.0f + __expf(-s_local_p[0]));
    const float sigg = 1.0f / (1.0f + __expf(-s_long_p[0]));
    const float SCL  = 0.18033688f;         // 0.125 * log2(e)

    if (tid < 128) nrm_l[tid] = mem_norm[(size_t)h * N_ + n0 + tid];

    // Q B-fragments for both strips (regs for whole kernel)
    const size_t q0 = ((size_t)bh * N_ + n0 + w * 32 + m) * 64;
    const size_t q1 = q0 + 16 * 64;
    bf16x8 qa00 = *(const bf16x8*)&qb[q0 + quad * 8];
    bf16x8 qa01 = *(const bf16x8*)&qb[q0 + 32 + quad * 8];
    bf16x8 qa10 = *(const bf16x8*)&qb[q1 + quad * 8];
    bf16x8 qa11 = *(const bf16x8*)&qb[q1 + 32 + quad * 8];

    f32x4 O0[4], O1[4];
    #pragma unroll
    for (int t = 0; t < 4; ++t) {
        f32x4 z = {0.f, 0.f, 0.f, 0.f};
        O0[t] = z; O1[t] = z;
    }
    float lsum0 = 0.f, lsum1 = 0.f;
    const int pr0 = w * 32, pr1 = w * 32 + 16;

    // DMA: this wave stages rows [w*16, w*16+16) of both K and V tiles
    const int r0 = w * 16 + (lane >> 3);   // row for op0 (op1 = +8)
    auto stage = [&](int c, int buf) {
        const __bf16* gk0 = kbp + ((size_t)c * 64 + r0) * 64 + (lane & 7) * 8;
        const __bf16* gv0 = vtp + (size_t)r0 * N_ + c * 64 + (lane & 7) * 8;
        char* lk = (char*)&Kt[buf][0] + w * 2048;
        char* lv = (char*)&Vt[buf][0] + w * 2048;
        gl2lds16(gk0,            lk);
        gl2lds16(gk0 + 8 * 64,   lk + 1024);
        gl2lds16(gv0,            lv);
        gl2lds16(gv0 + 8 * N_,   lv + 1024);
    };

    stage(0, 0);

    for (int c = 0; c < 32; ++c) {
        const int buf = c & 1;
        asm volatile("s_barrier" ::: "memory");      // all waves done with buf^1 reads
        if (c + 1 < 32) {
            stage(c + 1, buf ^ 1);
            asm volatile("s_waitcnt vmcnt(4)" ::: "memory");   // cur-buf DMAs done (own)
        } else {
            asm volatile("s_waitcnt vmcnt(0)" ::: "memory");
        }
        asm volatile("s_barrier" ::: "memory");      // everyone's cur-buf DMAs done
        const __bf16* Kc = &Kt[buf][0];
        const __bf16* Vc = &Vt[buf][0];

        // ---- S^T = K Q^T : K A-frags shared by both strips ----
        f32x4 s0[4], s1[4];
        #pragma unroll
        for (int t = 0; t < 4; ++t) {
            bf16x8 ka0 = *(const bf16x8*)&Kc[(t * 16 + m) * 64 + ((quad ^ sw) << 3)];
            bf16x8 ka1 = *(const bf16x8*)&Kc[(t * 16 + m) * 64 + (((4 + quad) ^ sw) << 3)];
            f32x4 z = {0.f, 0.f, 0.f, 0.f};
            z = __builtin_amdgcn_mfma_f32_16x16x32_bf16(ka0, qa00, z, 0, 0, 0);
            s0[t] = __builtin_amdgcn_mfma_f32_16x16x32_bf16(ka1, qa01, z, 0, 0, 0);
            f32x4 z2 = {0.f, 0.f, 0.f, 0.f};
            z2 = __builtin_amdgcn_mfma_f32_16x16x32_bf16(ka0, qa10, z2, 0, 0, 0);
            s1[t] = __builtin_amdgcn_mfma_f32_16x16x32_bf16(ka1, qa11, z2, 0, 0, 0);
        }

        // ---- p = exp2(s*scl); lsum; P -> strips (b64 writes) ----
        #pragma unroll
        for (int t = 0; t < 4; ++t) {
            float p0 = exp2f(s0[t][0] * SCL), p1 = exp2f(s0[t][1] * SCL);
            float p2 = exp2f(s0[t][2] * SCL), p3 = exp2f(s0[t][3] * SCL);
            lsum0 += p0 + p1 + p2 + p3;
            bf16x4 pk = {(__bf16)p0, (__bf16)p1, (__bf16)p2, (__bf16)p3};
            *(bf16x4*)&Pw[(pr0 + m) * KP + t * 16 + quad * 4] = pk;
            float r0_ = exp2f(s1[t][0] * SCL), r1_ = exp2f(s1[t][1] * SCL);
            float r2_ = exp2f(s1[t][2] * SCL), r3_ = exp2f(s1[t][3] * SCL);
            lsum1 += r0_ + r1_ + r2_ + r3_;
            bf16x4 rk = {(__bf16)r0_, (__bf16)r1_, (__bf16)r2_, (__bf16)r3_};
            *(bf16x4*)&Pw[(pr1 + m) * KP + t * 16 + quad * 4] = rk;
        }
        asm volatile("s_waitcnt lgkmcnt(0)" ::: "memory");

        // ---- O += P V : V B-frags shared by both strips ----
        #pragma unroll
        for (int c2 = 0; c2 < 2; ++c2) {
            bf16x8 pa0 = *(const bf16x8*)&Pw[(pr0 + m) * KP + c2 * 32 + quad * 8];
            bf16x8 pa1 = *(const bf16x8*)&Pw[(pr1 + m) * KP + c2 * 32 + quad * 8];
            #pragma unroll
            for (int t = 0; t < 4; ++t) {
                bf16x8 vv = *(const bf16x8*)&Vc[(t * 16 + m) * 64 +
                                                (((c2 * 4 + quad) ^ sw) << 3)];
                O0[t] = __builtin_amdgcn_mfma_f32_16x16x32_bf16(pa0, vv, O0[t], 0, 0, 0);
                O1[t] = __builtin_amdgcn_mfma_f32_16x16x32_bf16(pa1, vv, O1[t], 0, 0, 0);
            }
        }
    }

    // ---- lsum: reduce across quads ----
    lsum0 += __shfl_xor(lsum0, 16, 64); lsum0 += __shfl_xor(lsum0, 32, 64);
    lsum1 += __shfl_xor(lsum1, 16, 64); lsum1 += __shfl_xor(lsum1, 32, 64);
    if (lane < 16) { lsl[pr0 + lane] = lsum0; lsl[pr1 + lane] = lsum1; }

    // ---- stage mem^T, Gv^T into tile space (pitch 72, plain writes) ----
    __syncthreads();
    __bf16* MT = &Kt[0][0];      // 64*72 = 4608 elems, fits in Kt (8192)
    __bf16* GT = &Vt[0][0];
    for (int s2 = 0; s2 < 16; ++s2) {
        int flat = s2 * 256 + tid;          // flat = d*64 + e
        int d = flat >> 6, e = flat & 63;
        MT[e * KP + d] = (__bf16)mem[(size_t)h * 4096 + flat];
        GT[e * KP + d] = (__bf16)Gv[(size_t)bh * 4096 + flat];
    }
    __syncthreads();

    // ---- gated path per strip: num=eq@mem, mem_q=num/(eq*norm), o2=mem_q@Gv ----
    __bf16* op = o + ((size_t)bh * N_ + n0) * 64;
    #pragma unroll
    for (int s = 0; s < 2; ++s) {
        const int prs = w * 32 + s * 16;
        bf16x8 ea0, ea1;
        #pragma unroll
        for (int j = 0; j < 8; ++j) {
            ea0[j] = (__bf16)eluf((float)(s == 0 ? qa00[j] : qa10[j]));
            ea1[j] = (__bf16)eluf((float)(s == 0 ? qa01[j] : qa11[j]));
        }
        f32x4 num[4];
        #pragma unroll
        for (int t = 0; t < 4; ++t) {
            bf16x8 b0 = *(const bf16x8*)&MT[(t * 16 + m) * KP + quad * 8];
            bf16x8 b1 = *(const bf16x8*)&MT[(t * 16 + m) * KP + 32 + quad * 8];
            f32x4 z = {0.f, 0.f, 0.f, 0.f};
            z = __builtin_amdgcn_mfma_f32_16x16x32_bf16(ea0, b0, z, 0, 0, 0);
            num[t] = __builtin_amdgcn_mfma_f32_16x16x32_bf16(ea1, b1, z, 0, 0, 0);
        }
        *(bf16x8*)&Pw[(prs + m) * KP + quad * 8]      = ea0;
        *(bf16x8*)&Pw[(prs + m) * KP + 32 + quad * 8] = ea1;
        asm volatile("s_waitcnt lgkmcnt(0)" ::: "memory");
        float mq[4][4];
        #pragma unroll
        for (int t = 0; t < 4; ++t)
            #pragma unroll
            for (int r = 0; r < 4; ++r) {
                float eqv = (float)Pw[(prs + quad * 4 + r) * KP + t * 16 + m];
                mq[t][r] = num[t][r] / (eqv * nrm_l[prs + quad * 4 + r]);
            }
        #pragma unroll
        for (int t = 0; t < 4; ++t)
            #pragma unroll
            for (int r = 0; r < 4; ++r)
                Pw[(prs + quad * 4 + r) * KP + t * 16 + m] = (__bf16)mq[t][r];
        asm volatile("s_waitcnt lgkmcnt(0)" ::: "memory");
        bf16x8 ma0 = *(const bf16x8*)&Pw[(prs + m) * KP + quad * 8];
        bf16x8 ma1 = *(const bf16x8*)&Pw[(prs + m) * KP + 32 + quad * 8];

        #pragma unroll
        for (int t = 0; t < 4; ++t) {
            bf16x8 g0 = *(const bf16x8*)&GT[(t * 16 + m) * KP + quad * 8];
            bf16x8 g1 = *(const bf16x8*)&GT[(t * 16 + m) * KP + 32 + quad * 8];
            f32x4 z = {0.f, 0.f, 0.f, 0.f};
            z = __builtin_amdgcn_mfma_f32_16x16x32_bf16(ma0, g0, z, 0, 0, 0);
            f32x4 o2 = __builtin_amdgcn_mfma_f32_16x16x32_bf16(ma1, g1, z, 0, 0, 0);
            #pragma unroll
            for (int r = 0; r < 4; ++r) {
                const int qr = prs + quad * 4 + r;
                float val = ((s == 0) ? O0[t][r] : O1[t][r]) * (gl / lsl[qr])
                            + sigg * o2[r];
                op[(size_t)qr * 64 + t * 16 + m] = (__bf16)val;
            }
        }
    }
}

// ---------------- K5: output projection on MFMA (unchanged) ----------------
__global__ __launch_bounds__(256) void k_outproj(
    const __bf16* __restrict__ o, const float* __restrict__ Wo,
    const float* __restrict__ bo, float* __restrict__ out)
{
    const int row0 = blockIdx.x * 64;      // over B*N
    const int b = row0 >> 11, nb = row0 & 2047;
    __shared__ __align__(16) __bf16 WoS[64 * 40];   // [dout][k] per 32-k block
    const int tid  = threadIdx.x;
    const int w    = tid >> 6, lane = tid & 63;
    const int quad = lane >> 4, m = lane & 15;

    f32x4 acc[4];
    #pragma unroll
    for (int t = 0; t < 4; ++t) { f32x4 z = {0.f, 0.f, 0.f, 0.f}; acc[t] = z; }

    for (int kbk = 0; kbk < 16; ++kbk) {
        for (int s2 = 0; s2 < 8; ++s2) {
            int flat = s2 * 256 + tid;      // flat = n*32 + kk
            int n = flat >> 5, kk = flat & 31;
            WoS[n * 40 + kk] = (__bf16)Wo[(size_t)n * 512 + kbk * 32 + kk];
        }
        __syncthreads();
        const int hc = kbk >> 1;
        size_t arow = (((size_t)b * H_ + hc) * N_ + nb + w * 16 + m);
        bf16x8 af = *(const bf16x8*)&o[arow * 64 + (kbk & 1) * 32 + quad * 8];
        #pragma unroll
        for (int t = 0; t < 4; ++t) {
            bf16x8 bf_ = *(const bf16x8*)&WoS[(t * 16 + m) * 40 + quad * 8];
            acc[t] = __builtin_amdgcn_mfma_f32_16x16x32_bf16(af, bf_, acc[t], 0, 0, 0);
        }
        __syncthreads();
    }
    #pragma unroll
    for (int t = 0; t < 4; ++t) {
        float bias = bo[t * 16 + m];
        #pragma unroll
        for (int r = 0; r < 4; ++r)
            out[(size_t)(row0 + w * 16 + quad * 4 + r) * 64 + t * 16 + m] =
                acc[t][r] + bias;
    }
}

extern "C" void kernel_launch(void* const* d_in, const int* in_sizes, int n_in,
                              void* d_out, int out_size, void* d_ws, size_t ws_size,
                              hipStream_t stream)
{
    const float* q        = (const float*)d_in[0];
    const float* k        = (const float*)d_in[1];
    const float* v        = (const float*)d_in[2];
    const float* Wq       = (const float*)d_in[3];
    const float* Wk       = (const float*)d_in[4];
    const float* Wv       = (const float*)d_in[5];
    const float* Wo       = (const float*)d_in[6];
    const float* bo       = (const float*)d_in[7];
    const float* Wg       = (const float*)d_in[8];
    const float* s_local  = (const float*)d_in[9];
    const float* s_long   = (const float*)d_in[10];
    const float* mem      = (const float*)d_in[11];
    const float* mem_norm = (const float*)d_in[12];

    float* ws = (float*)d_ws;
    float*  kh  = ws;
    __bf16* qb  = (__bf16*)(ws + 4194304);
    __bf16* kb  = (__bf16*)(ws + 6291456);
    __bf16* vb  = (__bf16*)(ws + 8388608);
    __bf16* vbT = (__bf16*)(ws + 10485760);
    float*  Gv  = ws + 12582912;
    float*  pm  = ws + 12713984;
    float*  pg  = ws + 14811136;
    __bf16* o   = (__bf16*)(ws + 12713984);   // aliases pm (dead after k_reduce)

    float* out      = (float*)d_out;
    float* out_mem  = out + 524288;
    float* out_norm = out + 655360;

    k_proj   <<<dim3(128, 8, 3), 256, 0, stream>>>(q, k, v, Wq, Wk, Wv,
                                                   qb, kh, kb, vb, vbT);
    k_memacc <<<dim3(16, 32),    256, 0, stream>>>(kh, vb, mem, mem_norm,
                                                   pm, out_norm);
    k_gv     <<<dim3(16, 32),    256, 0, stream>>>(Wg, vbT, pg);
    k_reduce <<<dim3(512),       256, 0, stream>>>(mem, pm, pg, out_mem, Gv);
    k_flash  <<<dim3(16, 32),    256, 0, stream>>>(qb, kb, vbT, mem, mem_norm, Gv,
                                                   s_local, s_long, o);
    k_outproj<<<dim3(128),       256, 0, stream>>>(o, Wo, bo, out);
}

// Round 9
// 234.113 us; speedup vs baseline: 1.0126x; 1.0126x over previous
//
#include <hip/hip_runtime.h>
#include <math.h>

// InfiniAttention fused forward, MI355X round 9.
// B=4, N=2048, DIM=64, H=8, DH=64.
// Round-9: split-K flash. r6's k_flash inner loop (best measured: 71 us) kept
// byte-identical, but grid split over kv-columns: (16 qtiles, 2 K-halves,
// 32 bh) = 1024 blocks = 4 blocks/CU (r6 was grid-capped at 2). Blocks write
// unnormalized partial O (bf16) + partial row-sums (f32); new k_combine sums,
// normalizes, and runs the gated epilogue (moved from k_flash unchanged).
// k_proj/k_gv reverted to r6 (r8 swizzle removed); k_memacc/k_reduce/
// k_outproj byte-identical to round-6 PASS.
//
// Workspace (floats, 16908288 total = 67,633,152 B):
//   kh   @ 0         f32  4194304   -> Opart bf16 [half][bh][n][e] after k_memacc
//   qb   @ 4194304   bf16 [bh][n][d]
//   kb   @ 6291456   bf16 [bh][n][d]
//   vb   @ 8388608   bf16 [bh][n][d]
//   vbT  @ 10485760  bf16 [bh][e][n]
//   Gv   @ 12582912  f32  131072  [bh][d][e]
//   pm   @ 12713984  f32  2097152 (16 chunks)  <- o bf16 aliases pm
//   pg   @ 14811136  f32  2097152             <- lsp f32 [half][bh][n] after k_reduce

#define B_   4
#define N_   2048
#define H_   8
#define BH_  32
#define KP   72      // bf16 LDS pitch (144 B)

typedef __bf16 bf16x8 __attribute__((ext_vector_type(8)));
typedef __bf16 bf16x4 __attribute__((ext_vector_type(4)));
typedef float  f32x4  __attribute__((ext_vector_type(4)));

__device__ __forceinline__ float eluf(float x) {
    return x > 0.0f ? x : expm1f(x);   // expm1 critical near 0
}

// ---------------- K2: head projections (round-6 version) ----------
__global__ __launch_bounds__(256) void k_proj(
    const float* __restrict__ q, const float* __restrict__ k, const float* __restrict__ v,
    const float* __restrict__ Wq, const float* __restrict__ Wk, const float* __restrict__ Wv,
    __bf16* __restrict__ qb, float* __restrict__ kh, __bf16* __restrict__ kb,
    __bf16* __restrict__ vb, __bf16* __restrict__ vbT)
{
    const int which = blockIdx.z;
    const float* __restrict__ src = (which == 0) ? q : (which == 1) ? k : v;
    const float* __restrict__ W   = (which == 0) ? Wq : (which == 1) ? Wk : Wv;
    const int h    = blockIdx.y;
    const int row0 = blockIdx.x * 64;   // over B*N = 8192

    __shared__ __align__(16) float AsT[64][68];   // [dim][row]
    __shared__ __align__(16) float WsT[64][68];   // [dim][col]; reused for v^T
    const int tid = threadIdx.x;
    for (int s = 0; s < 16; ++s) {
        int flat = s * 256 + tid;
        int r = flat >> 6, d = flat & 63;
        AsT[d][r] = src[(size_t)(row0 + r) * 64 + d];
        WsT[d][r] = W[(size_t)(h * 64 + r) * 64 + d];
    }
    __syncthreads();

    const int ty = tid >> 4, tx = tid & 15;
    float acc[4][4];
    #pragma unroll
    for (int i = 0; i < 4; ++i)
        #pragma unroll
        for (int j = 0; j < 4; ++j) acc[i][j] = 0.0f;
    for (int kd = 0; kd < 64; ++kd) {
        float4 a4 = *(const float4*)&AsT[kd][ty * 4];
        float4 w4 = *(const float4*)&WsT[kd][tx * 4];
        float a[4] = {a4.x, a4.y, a4.z, a4.w};
        float w[4] = {w4.x, w4.y, w4.z, w4.w};
        #pragma unroll
        for (int i = 0; i < 4; ++i)
            #pragma unroll
            for (int j = 0; j < 4; ++j) acc[i][j] = fmaf(a[i], w[j], acc[i][j]);
    }

    const int b = row0 >> 11, nb = row0 & 2047;
    if (which == 0) {
        #pragma unroll
        for (int i = 0; i < 4; ++i) {
            size_t idx = ((((size_t)b * H_ + h) * N_ + nb + ty * 4 + i) << 6) + tx * 4;
            bf16x4 o4 = {(__bf16)acc[i][0], (__bf16)acc[i][1],
                         (__bf16)acc[i][2], (__bf16)acc[i][3]};
            *(bf16x4*)&qb[idx] = o4;
        }
    } else if (which == 1) {
        #pragma unroll
        for (int i = 0; i < 4; ++i) {
            size_t idx = ((((size_t)b * H_ + h) * N_ + nb + ty * 4 + i) << 6) + tx * 4;
            *(float4*)&kh[idx] = make_float4(acc[i][0], acc[i][1], acc[i][2], acc[i][3]);
            bf16x4 o4 = {(__bf16)acc[i][0], (__bf16)acc[i][1],
                         (__bf16)acc[i][2], (__bf16)acc[i][3]};
            *(bf16x4*)&kb[idx] = o4;
        }
    } else {
        #pragma unroll
        for (int i = 0; i < 4; ++i) {
            size_t idx = ((((size_t)b * H_ + h) * N_ + nb + ty * 4 + i) << 6) + tx * 4;
            bf16x4 o4 = {(__bf16)acc[i][0], (__bf16)acc[i][1],
                         (__bf16)acc[i][2], (__bf16)acc[i][3]};
            *(bf16x4*)&vb[idx] = o4;
        }
        __syncthreads();
        #pragma unroll
        for (int i = 0; i < 4; ++i)
            #pragma unroll
            for (int j = 0; j < 4; ++j) WsT[tx * 4 + j][ty * 4 + i] = acc[i][j];
        __syncthreads();
        const int e = tid >> 2, nc = (tid & 3) * 16;
        bf16x8 lo, hi;
        #pragma unroll
        for (int jj = 0; jj < 8; ++jj) {
            lo[jj] = (__bf16)WsT[e][nc + jj];
            hi[jj] = (__bf16)WsT[e][nc + 8 + jj];
        }
        size_t base = (((size_t)b * H_ + h) * 64 + e) * (size_t)N_ + nb + nc;
        *(bf16x8*)&vbT[base]     = lo;
        *(bf16x8*)&vbT[base + 8] = hi;
    }
}

// ---- K3: memory-update on split-bf16 MFMA (unchanged from round-6 PASS) ----
__global__ __launch_bounds__(256) void k_memacc(
    const float* __restrict__ kh, const __bf16* __restrict__ vb,
    const float* __restrict__ mem, const float* __restrict__ mem_norm,
    float* __restrict__ pmem, float* __restrict__ out_norm)
{
    const int chunk = blockIdx.x;    // 0..15
    const int bh    = blockIdx.y;
    const int h     = bh & 7;
    const int n0    = chunk * 128;

    __shared__ __align__(16) __bf16 memT_hi[64 * KP], memT_lo[64 * KP]; // [e][d]
    __shared__ __align__(16) __bf16 ekn_hi[64 * KP],  ekn_lo[64 * KP];  // [n][d]
    __shared__ __align__(16) __bf16 ekT_hi[64 * KP],  ekT_lo[64 * KP];  // [d][n]
    __shared__ __align__(16) __bf16 vtT_hi[64 * KP],  vtT_lo[64 * KP];  // [e][n]

    const int tid  = threadIdx.x;
    const int w    = tid >> 6, lane = tid & 63;
    const int quad = lane >> 4, m = lane & 15;

    for (int s = 0; s < 16; ++s) {
        int flat = s * 256 + tid;          // flat = d*64 + e
        int d = flat >> 6, e = flat & 63;
        float mv = mem[(size_t)h * 4096 + flat];
        __bf16 hi = (__bf16)mv;
        memT_hi[e * KP + d] = hi;
        memT_lo[e * KP + d] = (__bf16)(mv - (float)hi);
    }

    f32x4 accM[4];
    #pragma unroll
    for (int t = 0; t < 4; ++t) { f32x4 z = {0.f, 0.f, 0.f, 0.f}; accM[t] = z; }
    __syncthreads();

    for (int sub = 0; sub < 2; ++sub) {
        const int nb = n0 + sub * 64;
        for (int rr = w; rr < 64; rr += 4) {
            const int n = nb + rr;
            float ekv = eluf(kh[((size_t)bh * N_ + n) * 64 + lane]);
            __bf16 hi = (__bf16)ekv;
            __bf16 lo = (__bf16)(ekv - (float)hi);
            ekn_hi[rr * KP + lane] = hi;
            ekn_lo[rr * KP + lane] = lo;
            ekT_hi[lane * KP + rr] = hi;
            ekT_lo[lane * KP + rr] = lo;
            float srt = ekv;
            #pragma unroll
            for (int m2 = 32; m2; m2 >>= 1) srt += __shfl_xor(srt, m2, 64);
            if (lane == 0) out_norm[(size_t)bh * N_ + n] = srt;
        }
        __syncthreads();

        f32x4 km[4];
        #pragma unroll
        for (int t = 0; t < 4; ++t) { f32x4 z = {0.f, 0.f, 0.f, 0.f}; km[t] = z; }
        #pragma unroll
        for (int c2 = 0; c2 < 2; ++c2) {
            bf16x8 Ah = *(const bf16x8*)&ekn_hi[(w * 16 + m) * KP + c2 * 32 + quad * 8];
            bf16x8 Al = *(const bf16x8*)&ekn_lo[(w * 16 + m) * KP + c2 * 32 + quad * 8];
            #pragma unroll
            for (int et = 0; et < 4; ++et) {
                bf16x8 Bh = *(const bf16x8*)&memT_hi[(et * 16 + m) * KP + c2 * 32 + quad * 8];
                bf16x8 Bl = *(const bf16x8*)&memT_lo[(et * 16 + m) * KP + c2 * 32 + quad * 8];
                km[et] = __builtin_amdgcn_mfma_f32_16x16x32_bf16(Al, Bh, km[et], 0, 0, 0);
                km[et] = __builtin_amdgcn_mfma_f32_16x16x32_bf16(Ah, Bl, km[et], 0, 0, 0);
                km[et] = __builtin_amdgcn_mfma_f32_16x16x32_bf16(Ah, Bh, km[et], 0, 0, 0);
            }
        }
        float nrmv[4];
        #pragma unroll
        for (int r = 0; r < 4; ++r)
            nrmv[r] = mem_norm[(size_t)h * N_ + nb + w * 16 + quad * 4 + r];
        #pragma unroll
        for (int et = 0; et < 4; ++et) {
            #pragma unroll
            for (int r = 0; r < 4; ++r) {
                const int nl = w * 16 + quad * 4 + r;
                const int e  = et * 16 + m;
                float vh  = (float)vb[((size_t)bh * N_ + nb + nl) * 64 + e];
                float ekv = (float)ekn_hi[nl * KP + e] + (float)ekn_lo[nl * KP + e];
                float vt  = vh - km[et][r] / (ekv * nrmv[r]);
                __bf16 hi = (__bf16)vt;
                vtT_hi[e * KP + nl] = hi;
                vtT_lo[e * KP + nl] = (__bf16)(vt - (float)hi);
            }
        }
        __syncthreads();

        #pragma unroll
        for (int c2 = 0; c2 < 2; ++c2) {
            bf16x8 Ah = *(const bf16x8*)&ekT_hi[(w * 16 + m) * KP + c2 * 32 + quad * 8];
            bf16x8 Al = *(const bf16x8*)&ekT_lo[(w * 16 + m) * KP + c2 * 32 + quad * 8];
            #pragma unroll
            for (int et = 0; et < 4; ++et) {
                bf16x8 Bh = *(const bf16x8*)&vtT_hi[(et * 16 + m) * KP + c2 * 32 + quad * 8];
                bf16x8 Bl = *(const bf16x8*)&vtT_lo[(et * 16 + m) * KP + c2 * 32 + quad * 8];
                accM[et] = __builtin_amdgcn_mfma_f32_16x16x32_bf16(Al, Bh, accM[et], 0, 0, 0);
                accM[et] = __builtin_amdgcn_mfma_f32_16x16x32_bf16(Ah, Bl, accM[et], 0, 0, 0);
                accM[et] = __builtin_amdgcn_mfma_f32_16x16x32_bf16(Ah, Bh, accM[et], 0, 0, 0);
            }
        }
        __syncthreads();
    }

    const size_t base = ((size_t)chunk * BH_ + bh) * 4096;
    #pragma unroll
    for (int et = 0; et < 4; ++et)
        #pragma unroll
        for (int r = 0; r < 4; ++r)
            pmem[base + (size_t)(w * 16 + quad * 4 + r) * 64 + et * 16 + m] =
                accM[et][r];
}

// ---- K3g: Gv partials = Wg^T @ vh (round-6 version) ----
__global__ __launch_bounds__(256) void k_gv(
    const float* __restrict__ Wg, const __bf16* __restrict__ vbT,
    float* __restrict__ pGv)
{
    const int chunk = blockIdx.x;    // 0..15
    const int bh    = blockIdx.y;
    const int n0    = chunk * 128;
    __shared__ __align__(16) __bf16 WgT[64 * 136];   // [d][n], pitch 272B
    const int tid  = threadIdx.x;
    const int w    = tid >> 6, lane = tid & 63;
    const int quad = lane >> 4, m = tid & 15;

    for (int s = 0; s < 8; ++s) {
        int f4 = s * 256 + tid;
        int n = f4 >> 4, dg = (f4 & 15) * 4;
        float4 wv = *(const float4*)&Wg[(size_t)(n0 + n) * 64 + dg];
        WgT[(dg + 0) * 136 + n] = (__bf16)wv.x;
        WgT[(dg + 1) * 136 + n] = (__bf16)wv.y;
        WgT[(dg + 2) * 136 + n] = (__bf16)wv.z;
        WgT[(dg + 3) * 136 + n] = (__bf16)wv.w;
    }
    __syncthreads();

    f32x4 acc[4];
    #pragma unroll
    for (int t = 0; t < 4; ++t) { f32x4 z = {0.f, 0.f, 0.f, 0.f}; acc[t] = z; }
    #pragma unroll
    for (int c = 0; c < 4; ++c) {
        bf16x8 Af = *(const bf16x8*)&WgT[(w * 16 + m) * 136 + c * 32 + quad * 8];
        #pragma unroll
        for (int et = 0; et < 4; ++et) {
            bf16x8 Bf = *(const bf16x8*)&vbT[((size_t)bh * 64 + et * 16 + m) * N_ +
                                             n0 + c * 32 + quad * 8];
            acc[et] = __builtin_amdgcn_mfma_f32_16x16x32_bf16(Af, Bf, acc[et], 0, 0, 0);
        }
    }
    const size_t base = ((size_t)chunk * BH_ + bh) * 4096;
    #pragma unroll
    for (int et = 0; et < 4; ++et)
        #pragma unroll
        for (int r = 0; r < 4; ++r)
            pGv[base + (size_t)(w * 16 + quad * 4 + r) * 64 + et * 16 + m] =
                acc[et][r];
}

// ---------------- K3b: reduce partials (unchanged) ----------------
__global__ __launch_bounds__(256) void k_reduce(
    const float* __restrict__ mem, const float* __restrict__ pmem,
    const float* __restrict__ pGv, float* __restrict__ out_mem, float* __restrict__ Gv)
{
    const int idx = blockIdx.x * 256 + threadIdx.x;
    const int bh = idx >> 12, h = bh & 7, de = idx & 4095;
    float sm = mem[(size_t)h * 4096 + de];
    float sg = 0.0f;
    #pragma unroll
    for (int c = 0; c < 16; ++c) {
        sm += pmem[(size_t)c * 131072 + idx];
        sg += pGv[(size_t)c * 131072 + idx];
    }
    out_mem[idx] = sm;
    Gv[idx] = sg;
}

// ---------- K4: flash attention, split-K (r6 inner loop, 4 blocks/CU) ----------
// grid (16, 2, 32): x = 128-row q tile, y = kv half (16 tiles), z = bh.
// Writes unnormalized partial O (bf16) + partial row-sums (f32).
__global__ __launch_bounds__(256, 4) void k_flash(
    const __bf16* __restrict__ qb, const __bf16* __restrict__ kb,
    const __bf16* __restrict__ vbT, __bf16* __restrict__ Opart,
    float* __restrict__ lsp)
{
    const int n0   = blockIdx.x * 128;
    const int half = blockIdx.y;
    const int bh   = blockIdx.z;
    const __bf16* __restrict__ kbp = kb  + (size_t)bh * N_ * 64;
    const __bf16* __restrict__ vtp = vbT + (size_t)bh * 64 * N_;

    __shared__ __align__(16) __bf16 Kb[64 * KP];    // [kcol][d]
    __shared__ __align__(16) __bf16 VT[64 * KP];    // [e][n]
    __shared__ __align__(16) __bf16 Pw[128 * KP];   // [qrow][kcol] per-wave strips

    const int tid  = threadIdx.x;
    const int w    = tid >> 6, lane = tid & 63;
    const int quad = lane >> 4, m = lane & 15;
    const float SCL = 0.18033688f;    // 0.125 * log2(e)

    // Q B-fragments for both strips (regs for whole kernel)
    const size_t q0 = ((size_t)bh * N_ + n0 + w * 32 + m) * 64;
    const size_t q1 = q0 + 16 * 64;
    bf16x8 qa00 = *(const bf16x8*)&qb[q0 + quad * 8];
    bf16x8 qa01 = *(const bf16x8*)&qb[q0 + 32 + quad * 8];
    bf16x8 qa10 = *(const bf16x8*)&qb[q1 + quad * 8];
    bf16x8 qa11 = *(const bf16x8*)&qb[q1 + 32 + quad * 8];

    f32x4 O0[4], O1[4];
    #pragma unroll
    for (int t = 0; t < 4; ++t) {
        f32x4 z = {0.f, 0.f, 0.f, 0.f};
        O0[t] = z; O1[t] = z;
    }
    float lsum0 = 0.f, lsum1 = 0.f;
    const int pr0 = w * 32, pr1 = w * 32 + 16;

    const int srow = tid >> 2, scg = (tid & 3) * 16;
    const int c0 = half * 16;
    bf16x8 pk0 = *(const bf16x8*)&kbp[(size_t)(c0 * 64 + srow) * 64 + scg];
    bf16x8 pk1 = *(const bf16x8*)&kbp[(size_t)(c0 * 64 + srow) * 64 + scg + 8];
    bf16x8 pv0 = *(const bf16x8*)&vtp[(size_t)srow * N_ + c0 * 64 + scg];
    bf16x8 pv1 = *(const bf16x8*)&vtp[(size_t)srow * N_ + c0 * 64 + scg + 8];

    for (int cc = 0; cc < 16; ++cc) {
        const int c = c0 + cc;
        __syncthreads();
        *(bf16x8*)&Kb[srow * KP + scg]     = pk0;
        *(bf16x8*)&Kb[srow * KP + scg + 8] = pk1;
        *(bf16x8*)&VT[srow * KP + scg]     = pv0;
        *(bf16x8*)&VT[srow * KP + scg + 8] = pv1;
        __syncthreads();
        if (cc + 1 < 16) {
            const size_t kn = (size_t)((c + 1) * 64 + srow) * 64 + scg;
            const size_t vn = (size_t)srow * N_ + (c + 1) * 64 + scg;
            pk0 = *(const bf16x8*)&kbp[kn];
            pk1 = *(const bf16x8*)&kbp[kn + 8];
            pv0 = *(const bf16x8*)&vtp[vn];
            pv1 = *(const bf16x8*)&vtp[vn + 8];
        }

        // ---- S^T = K Q^T : K A-frags shared by both strips ----
        f32x4 s0[4], s1[4];
        #pragma unroll
        for (int t = 0; t < 4; ++t) {
            bf16x8 ka0 = *(const bf16x8*)&Kb[(t * 16 + m) * KP + quad * 8];
            bf16x8 ka1 = *(const bf16x8*)&Kb[(t * 16 + m) * KP + 32 + quad * 8];
            f32x4 z = {0.f, 0.f, 0.f, 0.f};
            z = __builtin_amdgcn_mfma_f32_16x16x32_bf16(ka0, qa00, z, 0, 0, 0);
            s0[t] = __builtin_amdgcn_mfma_f32_16x16x32_bf16(ka1, qa01, z, 0, 0, 0);
            f32x4 z2 = {0.f, 0.f, 0.f, 0.f};
            z2 = __builtin_amdgcn_mfma_f32_16x16x32_bf16(ka0, qa10, z2, 0, 0, 0);
            s1[t] = __builtin_amdgcn_mfma_f32_16x16x32_bf16(ka1, qa11, z2, 0, 0, 0);
        }

        // ---- p = exp2(s*scl); lsum; P -> strips (b64 writes) ----
        #pragma unroll
        for (int t = 0; t < 4; ++t) {
            float p0 = exp2f(s0[t][0] * SCL), p1 = exp2f(s0[t][1] * SCL);
            float p2 = exp2f(s0[t][2] * SCL), p3 = exp2f(s0[t][3] * SCL);
            lsum0 += p0 + p1 + p2 + p3;
            bf16x4 pk = {(__bf16)p0, (__bf16)p1, (__bf16)p2, (__bf16)p3};
            *(bf16x4*)&Pw[(pr0 + m) * KP + t * 16 + quad * 4] = pk;
            float r0 = exp2f(s1[t][0] * SCL), r1 = exp2f(s1[t][1] * SCL);
            float r2 = exp2f(s1[t][2] * SCL), r3 = exp2f(s1[t][3] * SCL);
            lsum1 += r0 + r1 + r2 + r3;
            bf16x4 rk = {(__bf16)r0, (__bf16)r1, (__bf16)r2, (__bf16)r3};
            *(bf16x4*)&Pw[(pr1 + m) * KP + t * 16 + quad * 4] = rk;
        }
        asm volatile("s_waitcnt lgkmcnt(0)" ::: "memory");

        // ---- O += P V : V B-frags shared by both strips ----
        #pragma unroll
        for (int c2 = 0; c2 < 2; ++c2) {
            bf16x8 pa0 = *(const bf16x8*)&Pw[(pr0 + m) * KP + c2 * 32 + quad * 8];
            bf16x8 pa1 = *(const bf16x8*)&Pw[(pr1 + m) * KP + c2 * 32 + quad * 8];
            #pragma unroll
            for (int t = 0; t < 4; ++t) {
                bf16x8 vv = *(const bf16x8*)&VT[(t * 16 + m) * KP + c2 * 32 + quad * 8];
                O0[t] = __builtin_amdgcn_mfma_f32_16x16x32_bf16(pa0, vv, O0[t], 0, 0, 0);
                O1[t] = __builtin_amdgcn_mfma_f32_16x16x32_bf16(pa1, vv, O1[t], 0, 0, 0);
            }
        }
    }

    // ---- partial lsum: reduce across quads; scatter to global ----
    lsum0 += __shfl_xor(lsum0, 16, 64); lsum0 += __shfl_xor(lsum0, 32, 64);
    lsum1 += __shfl_xor(lsum1, 16, 64); lsum1 += __shfl_xor(lsum1, 32, 64);
    const size_t lbase = ((size_t)half * BH_ + bh) * N_ + n0;
    if (lane < 16) {
        lsp[lbase + pr0 + lane] = lsum0;
        lsp[lbase + pr1 + lane] = lsum1;
    }

    // ---- partial O: raw (unnormalized) bf16 store ----
    __bf16* op = Opart + (((size_t)half * BH_ + bh) * N_ + n0) * 64;
    #pragma unroll
    for (int t = 0; t < 4; ++t)
        #pragma unroll
        for (int r = 0; r < 4; ++r) {
            op[(size_t)(pr0 + quad * 4 + r) * 64 + t * 16 + m] = (__bf16)O0[t][r];
            op[(size_t)(pr1 + quad * 4 + r) * 64 + t * 16 + m] = (__bf16)O1[t][r];
        }
}

// ---------- K4b: combine halves + gated compressive-memory epilogue ----------
// grid (32, 32): x = 64-row tile, y = bh. 4 waves, one 16-row strip each.
__global__ __launch_bounds__(256, 4) void k_combine(
    const __bf16* __restrict__ Opart, const float* __restrict__ lsp,
    const __bf16* __restrict__ qb, const float* __restrict__ mem,
    const float* __restrict__ mem_norm, const float* __restrict__ Gv,
    const float* __restrict__ s_local_p, const float* __restrict__ s_long_p,
    __bf16* __restrict__ o)
{
    const int n0 = blockIdx.x * 64;
    const int bh = blockIdx.y;
    const int h  = bh & 7;

    __shared__ __align__(16) __bf16 MT[64 * KP];   // mem^T [e][d]
    __shared__ __align__(16) __bf16 GT[64 * KP];   // Gv^T  [e][d]
    __shared__ __align__(16) __bf16 Pc[64 * KP];   // scratch: eq/mq strips, then o2 col-major
    __shared__ float lsl[64];
    __shared__ float nrm_l[64];

    const int tid  = threadIdx.x;
    const int w    = tid >> 6, lane = tid & 63;
    const int quad = lane >> 4, m = lane & 15;
    const float gl   = 1.0f - 1.0f / (1.0f + __expf(-s_local_p[0]));
    const float sigg = 1.0f / (1.0f + __expf(-s_long_p[0]));

    if (tid < 64) {
        lsl[tid] = lsp[(size_t)bh * N_ + n0 + tid] +
                   lsp[((size_t)BH_ + bh) * N_ + n0 + tid];
        nrm_l[tid] = mem_norm[(size_t)h * N_ + n0 + tid];
    }
    for (int s2 = 0; s2 < 16; ++s2) {
        int flat = s2 * 256 + tid;          // flat = d*64 + e
        int d = flat >> 6, e = flat & 63;
        MT[e * KP + d] = (__bf16)mem[(size_t)h * 4096 + flat];
        GT[e * KP + d] = (__bf16)Gv[(size_t)bh * 4096 + flat];
    }
    __syncthreads();

    // ---- gated path, one strip per wave ----
    const int prow = w * 16;
    const size_t qo = ((size_t)bh * N_ + n0 + prow + m) * 64;
    bf16x8 qa0 = *(const bf16x8*)&qb[qo + quad * 8];
    bf16x8 qa1 = *(const bf16x8*)&qb[qo + 32 + quad * 8];
    bf16x8 ea0, ea1;
    #pragma unroll
    for (int j = 0; j < 8; ++j) {
        ea0[j] = (__bf16)eluf((float)qa0[j]);
        ea1[j] = (__bf16)eluf((float)qa1[j]);
    }
    f32x4 num[4];
    #pragma unroll
    for (int t = 0; t < 4; ++t) {
        bf16x8 b0 = *(const bf16x8*)&MT[(t * 16 + m) * KP + quad * 8];
        bf16x8 b1 = *(const bf16x8*)&MT[(t * 16 + m) * KP + 32 + quad * 8];
        f32x4 z = {0.f, 0.f, 0.f, 0.f};
        z = __builtin_amdgcn_mfma_f32_16x16x32_bf16(ea0, b0, z, 0, 0, 0);
        num[t] = __builtin_amdgcn_mfma_f32_16x16x32_bf16(ea1, b1, z, 0, 0, 0);
    }
    *(bf16x8*)&Pc[(prow + m) * KP + quad * 8]      = ea0;
    *(bf16x8*)&Pc[(prow + m) * KP + 32 + quad * 8] = ea1;
    asm volatile("s_waitcnt lgkmcnt(0)" ::: "memory");
    float mq[4][4];
    #pragma unroll
    for (int t = 0; t < 4; ++t)
        #pragma unroll
        for (int r = 0; r < 4; ++r) {
            float eqv = (float)Pc[(prow + quad * 4 + r) * KP + t * 16 + m];
            mq[t][r] = num[t][r] / (eqv * nrm_l[prow + quad * 4 + r]);
        }
    #pragma unroll
    for (int t = 0; t < 4; ++t)
        #pragma unroll
        for (int r = 0; r < 4; ++r)
            Pc[(prow + quad * 4 + r) * KP + t * 16 + m] = (__bf16)mq[t][r];
    asm volatile("s_waitcnt lgkmcnt(0)" ::: "memory");
    bf16x8 ma0 = *(const bf16x8*)&Pc[(prow + m) * KP + quad * 8];
    bf16x8 ma1 = *(const bf16x8*)&Pc[(prow + m) * KP + 32 + quad * 8];
    __syncthreads();     // all waves done with Pc row-major before col-major reuse

    f32x4 o2[4];
    #pragma unroll
    for (int t = 0; t < 4; ++t) {
        bf16x8 g0 = *(const bf16x8*)&GT[(t * 16 + m) * KP + quad * 8];
        bf16x8 g1 = *(const bf16x8*)&GT[(t * 16 + m) * KP + 32 + quad * 8];
        f32x4 z = {0.f, 0.f, 0.f, 0.f};
        z = __builtin_amdgcn_mfma_f32_16x16x32_bf16(ma0, g0, z, 0, 0, 0);
        o2[t] = __builtin_amdgcn_mfma_f32_16x16x32_bf16(ma1, g1, z, 0, 0, 0);
    }
    // store sigg*o2 into Pc COL-MAJOR [col][row] (b64 packs along r)
    #pragma unroll
    for (int t = 0; t < 4; ++t) {
        bf16x4 pk = {(__bf16)(sigg * o2[t][0]), (__bf16)(sigg * o2[t][1]),
                     (__bf16)(sigg * o2[t][2]), (__bf16)(sigg * o2[t][3])};
        *(bf16x4*)&Pc[(t * 16 + m) * KP + prow + quad * 4] = pk;
    }
    __syncthreads();

    // ---- phase B: o = (Oa+Ob)*(gl/ls) + o2s, fully vectorized global I/O ----
    const int row = tid >> 2, ec = (tid & 3) * 16;
    const float scale = gl / lsl[row];
    const size_t gbase = ((size_t)bh * N_ + n0 + row) * 64 + ec;
    const size_t hoff  = (size_t)BH_ * N_ * 64;
    bf16x8 a0 = *(const bf16x8*)&Opart[gbase];
    bf16x8 a1 = *(const bf16x8*)&Opart[gbase + 8];
    bf16x8 b0 = *(const bf16x8*)&Opart[hoff + gbase];
    bf16x8 b1 = *(const bf16x8*)&Opart[hoff + gbase + 8];
    bf16x8 r0, r1;
    #pragma unroll
    for (int j = 0; j < 8; ++j) {
        r0[j] = (__bf16)(((float)a0[j] + (float)b0[j]) * scale +
                         (float)Pc[(ec + j) * KP + row]);
        r1[j] = (__bf16)(((float)a1[j] + (float)b1[j]) * scale +
                         (float)Pc[(ec + 8 + j) * KP + row]);
    }
    *(bf16x8*)&o[gbase]     = r0;
    *(bf16x8*)&o[gbase + 8] = r1;
}

// ---------------- K5: output projection on MFMA (unchanged) ----------------
__global__ __launch_bounds__(256) void k_outproj(
    const __bf16* __restrict__ o, const float* __restrict__ Wo,
    const float* __restrict__ bo, float* __restrict__ out)
{
    const int row0 = blockIdx.x * 64;      // over B*N
    const int b = row0 >> 11, nb = row0 & 2047;
    __shared__ __align__(16) __bf16 WoS[64 * 40];   // [dout][k] per 32-k block
    const int tid  = threadIdx.x;
    const int w    = tid >> 6, lane = tid & 63;
    const int quad = lane >> 4, m = lane & 15;

    f32x4 acc[4];
    #pragma unroll
    for (int t = 0; t < 4; ++t) { f32x4 z = {0.f, 0.f, 0.f, 0.f}; acc[t] = z; }

    for (int kbk = 0; kbk < 16; ++kbk) {
        for (int s2 = 0; s2 < 8; ++s2) {
            int flat = s2 * 256 + tid;      // flat = n*32 + kk
            int n = flat >> 5, kk = flat & 31;
            WoS[n * 40 + kk] = (__bf16)Wo[(size_t)n * 512 + kbk * 32 + kk];
        }
        __syncthreads();
        const int hc = kbk >> 1;
        size_t arow = (((size_t)b * H_ + hc) * N_ + nb + w * 16 + m);
        bf16x8 af = *(const bf16x8*)&o[arow * 64 + (kbk & 1) * 32 + quad * 8];
        #pragma unroll
        for (int t = 0; t < 4; ++t) {
            bf16x8 bf_ = *(const bf16x8*)&WoS[(t * 16 + m) * 40 + quad * 8];
            acc[t] = __builtin_amdgcn_mfma_f32_16x16x32_bf16(af, bf_, acc[t], 0, 0, 0);
        }
        __syncthreads();
    }
    #pragma unroll
    for (int t = 0; t < 4; ++t) {
        float bias = bo[t * 16 + m];
        #pragma unroll
        for (int r = 0; r < 4; ++r)
            out[(size_t)(row0 + w * 16 + quad * 4 + r) * 64 + t * 16 + m] =
                acc[t][r] + bias;
    }
}

extern "C" void kernel_launch(void* const* d_in, const int* in_sizes, int n_in,
                              void* d_out, int out_size, void* d_ws, size_t ws_size,
                              hipStream_t stream)
{
    const float* q        = (const float*)d_in[0];
    const float* k        = (const float*)d_in[1];
    const float* v        = (const float*)d_in[2];
    const float* Wq       = (const float*)d_in[3];
    const float* Wk       = (const float*)d_in[4];
    const float* Wv       = (const float*)d_in[5];
    const float* Wo       = (const float*)d_in[6];
    const float* bo       = (const float*)d_in[7];
    const float* Wg       = (const float*)d_in[8];
    const float* s_local  = (const float*)d_in[9];
    const float* s_long   = (const float*)d_in[10];
    const float* mem      = (const float*)d_in[11];
    const float* mem_norm = (const float*)d_in[12];

    float* ws = (float*)d_ws;
    float*  kh    = ws;                         // dead after k_memacc
    __bf16* Opart = (__bf16*)ws;                // reuses kh region (exact fit)
    __bf16* qb    = (__bf16*)(ws + 4194304);
    __bf16* kb    = (__bf16*)(ws + 6291456);
    __bf16* vb    = (__bf16*)(ws + 8388608);
    __bf16* vbT   = (__bf16*)(ws + 10485760);
    float*  Gv    = ws + 12582912;
    float*  pm    = ws + 12713984;
    float*  pg    = ws + 14811136;              // dead after k_reduce
    float*  lsp   = ws + 14811136;              // reuses pg region
    __bf16* o     = (__bf16*)(ws + 12713984);   // aliases pm (dead after k_reduce)

    float* out      = (float*)d_out;
    float* out_mem  = out + 524288;
    float* out_norm = out + 655360;

    k_proj   <<<dim3(128, 8, 3), 256, 0, stream>>>(q, k, v, Wq, Wk, Wv,
                                                   qb, kh, kb, vb, vbT);
    k_memacc <<<dim3(16, 32),    256, 0, stream>>>(kh, vb, mem, mem_norm,
                                                   pm, out_norm);
    k_gv     <<<dim3(16, 32),    256, 0, stream>>>(Wg, vbT, pg);
    k_reduce <<<dim3(512),       256, 0, stream>>>(mem, pm, pg, out_mem, Gv);
    k_flash  <<<dim3(16, 2, 32), 256, 0, stream>>>(qb, kb, vbT, Opart, lsp);
    k_combine<<<dim3(32, 32),    256, 0, stream>>>(Opart, lsp, qb, mem, mem_norm,
                                                   Gv, s_local, s_long, o);
    k_outproj<<<dim3(128),       256, 0, stream>>>(o, Wo, bo, out);
}

// Round 10
// 217.418 us; speedup vs baseline: 1.0904x; 1.0768x over previous
//
#include <hip/hip_runtime.h>
#include <math.h>

// InfiniAttention fused forward, MI355X round 10.
// B=4, N=2048, DIM=64, H=8, DH=64.
// Round-10 = round-6 pipeline (best: 221.7 us; split-K r9 reverted — its
// Opart round-trip cost +19 us vs -6 gained) with three cuts:
//  (1) k_memacc: out_norm via MFMA ones-column (replaces 6-shfl x16 chain;
//      loose threshold), v_term divide -> rcp*mul (error ~1e4 vs 2.1e7).
//  (2) k_proj v-path -> bf16 MFMA (v feeds only loose consumers).
//      q/k keep the exact f32 chain (tiny elu(q)/elu(k) divisors demand
//      RELATIVE accuracy; bf16-input MFMA would inject ~1e-3 absolute).
//  (3) kb pre-scaled by 0.125*log2(e) -> k_flash softmax is bare exp2f(s).
//
// Workspace (floats, 16908288 total = 67,633,152 B):
//   kh   @ 0         f32  4194304
//   qb   @ 4194304   bf16 [bh][n][d]
//   kb   @ 6291456   bf16 [bh][n][d]  (pre-scaled by 0.1803...)
//   vb   @ 8388608   bf16 [bh][n][d]
//   vbT  @ 10485760  bf16 [bh][e][n]
//   Gv   @ 12582912  f32  131072  [bh][d][e]
//   pm   @ 12713984  f32  2097152 (16 chunks)  <- o bf16 aliases pm
//   pg   @ 14811136  f32  2097152

#define B_   4
#define N_   2048
#define H_   8
#define BH_  32
#define KP   72      // bf16 LDS pitch (144 B)
#define SCLK 0.18033688f   // 0.125 * log2(e), folded into kb

typedef __bf16 bf16x8 __attribute__((ext_vector_type(8)));
typedef __bf16 bf16x4 __attribute__((ext_vector_type(4)));
typedef float  f32x4  __attribute__((ext_vector_type(4)));

__device__ __forceinline__ float eluf(float x) {
    return x > 0.0f ? x : expm1f(x);   // expm1 critical near 0
}

// ---------------- K2: head projections -----------------
// which==0 (q), which==1 (k): exact sequential f32 FMA chain (k bit-matched
// to np sgemm; q needs relative accuracy for tiny elu(q) divisors).
// which==2 (v): bf16 MFMA, no f32 staging (loose consumers only).
__global__ __launch_bounds__(256) void k_proj(
    const float* __restrict__ q, const float* __restrict__ k, const float* __restrict__ v,
    const float* __restrict__ Wq, const float* __restrict__ Wk, const float* __restrict__ Wv,
    __bf16* __restrict__ qb, float* __restrict__ kh, __bf16* __restrict__ kb,
    __bf16* __restrict__ vb, __bf16* __restrict__ vbT)
{
    const int which = blockIdx.z;
    const int h    = blockIdx.y;
    const int row0 = blockIdx.x * 64;   // over B*N = 8192
    const int tid  = threadIdx.x;
    const int b = row0 >> 11, nb = row0 & 2047;

    __shared__ __align__(16) float  AsT[64][68];   // [dim][row] (q/k path)
    __shared__ __align__(16) float  WsT[64][68];   // [dim][col] (q/k path)
    __shared__ __align__(16) __bf16 Cs[64 * 72];   // C bounce (v path)

    if (which == 2) {
        // ---- v: bf16 MFMA ----
        const int w = tid >> 6, lane = tid & 63;
        const int quad = lane >> 4, m = lane & 15;
        const float* ar = v + (size_t)(row0 + w * 16 + m) * 64;
        bf16x8 a0, a1;
        #pragma unroll
        for (int j = 0; j < 8; ++j) {
            a0[j] = (__bf16)ar[quad * 8 + j];
            a1[j] = (__bf16)ar[32 + quad * 8 + j];
        }
        f32x4 acc[4];
        #pragma unroll
        for (int t = 0; t < 4; ++t) {
            const float* wr = Wv + (size_t)(h * 64 + t * 16 + m) * 64;
            bf16x8 b0, b1;
            #pragma unroll
            for (int j = 0; j < 8; ++j) {
                b0[j] = (__bf16)wr[quad * 8 + j];
                b1[j] = (__bf16)wr[32 + quad * 8 + j];
            }
            f32x4 z = {0.f, 0.f, 0.f, 0.f};
            z = __builtin_amdgcn_mfma_f32_16x16x32_bf16(a0, b0, z, 0, 0, 0);
            acc[t] = __builtin_amdgcn_mfma_f32_16x16x32_bf16(a1, b1, z, 0, 0, 0);
        }
        #pragma unroll
        for (int t = 0; t < 4; ++t)
            #pragma unroll
            for (int r = 0; r < 4; ++r)
                Cs[(w * 16 + quad * 4 + r) * 72 + t * 16 + m] = (__bf16)acc[t][r];
        __syncthreads();
        // row-major -> vb
        const int rr = tid >> 2, csg = (tid & 3) * 16;
        bf16x8 r0 = *(const bf16x8*)&Cs[rr * 72 + csg];
        bf16x8 r1 = *(const bf16x8*)&Cs[rr * 72 + csg + 8];
        size_t gb = ((((size_t)b * H_ + h) * N_ + nb + rr) << 6) + csg;
        *(bf16x8*)&vb[gb]     = r0;
        *(bf16x8*)&vb[gb + 8] = r1;
        // col-major -> vbT
        const int e = tid >> 2, ns = (tid & 3) * 16;
        bf16x8 t0, t1;
        #pragma unroll
        for (int j = 0; j < 8; ++j) {
            t0[j] = Cs[(ns + j) * 72 + e];
            t1[j] = Cs[(ns + 8 + j) * 72 + e];
        }
        size_t base = (((size_t)b * H_ + h) * 64 + e) * (size_t)N_ + nb + ns;
        *(bf16x8*)&vbT[base]     = t0;
        *(bf16x8*)&vbT[base + 8] = t1;
        return;
    }

    // ---- q / k: exact f32 chain (byte-identical math to round-2..9 PASS) ----
    const float* __restrict__ src = (which == 0) ? q : k;
    const float* __restrict__ W   = (which == 0) ? Wq : Wk;
    for (int s = 0; s < 16; ++s) {
        int flat = s * 256 + tid;
        int r = flat >> 6, d = flat & 63;
        AsT[d][r] = src[(size_t)(row0 + r) * 64 + d];
        WsT[d][r] = W[(size_t)(h * 64 + r) * 64 + d];
    }
    __syncthreads();

    const int ty = tid >> 4, tx = tid & 15;
    float acc[4][4];
    #pragma unroll
    for (int i = 0; i < 4; ++i)
        #pragma unroll
        for (int j = 0; j < 4; ++j) acc[i][j] = 0.0f;
    for (int kd = 0; kd < 64; ++kd) {
        float4 a4 = *(const float4*)&AsT[kd][ty * 4];
        float4 w4 = *(const float4*)&WsT[kd][tx * 4];
        float a[4] = {a4.x, a4.y, a4.z, a4.w};
        float w[4] = {w4.x, w4.y, w4.z, w4.w};
        #pragma unroll
        for (int i = 0; i < 4; ++i)
            #pragma unroll
            for (int j = 0; j < 4; ++j) acc[i][j] = fmaf(a[i], w[j], acc[i][j]);
    }

    if (which == 0) {
        #pragma unroll
        for (int i = 0; i < 4; ++i) {
            size_t idx = ((((size_t)b * H_ + h) * N_ + nb + ty * 4 + i) << 6) + tx * 4;
            bf16x4 o4 = {(__bf16)acc[i][0], (__bf16)acc[i][1],
                         (__bf16)acc[i][2], (__bf16)acc[i][3]};
            *(bf16x4*)&qb[idx] = o4;
        }
    } else {
        #pragma unroll
        for (int i = 0; i < 4; ++i) {
            size_t idx = ((((size_t)b * H_ + h) * N_ + nb + ty * 4 + i) << 6) + tx * 4;
            *(float4*)&kh[idx] = make_float4(acc[i][0], acc[i][1], acc[i][2], acc[i][3]);
            bf16x4 o4 = {(__bf16)(acc[i][0] * SCLK), (__bf16)(acc[i][1] * SCLK),
                         (__bf16)(acc[i][2] * SCLK), (__bf16)(acc[i][3] * SCLK)};
            *(bf16x4*)&kb[idx] = o4;
        }
    }
}

// ---- K3: memory-update on split-bf16 MFMA (16 chunks of 128 rows) ----
// r10: out_norm via MFMA ones-column (loose), v_term divide -> rcp*mul.
// ek/km/accM math otherwise identical to round-6 PASS.
__global__ __launch_bounds__(256) void k_memacc(
    const float* __restrict__ kh, const __bf16* __restrict__ vb,
    const float* __restrict__ mem, const float* __restrict__ mem_norm,
    float* __restrict__ pmem, float* __restrict__ out_norm)
{
    const int chunk = blockIdx.x;    // 0..15
    const int bh    = blockIdx.y;
    const int h     = bh & 7;
    const int n0    = chunk * 128;

    __shared__ __align__(16) __bf16 memT_hi[64 * KP], memT_lo[64 * KP]; // [e][d]
    __shared__ __align__(16) __bf16 ekn_hi[64 * KP],  ekn_lo[64 * KP];  // [n][d]
    __shared__ __align__(16) __bf16 ekT_hi[64 * KP],  ekT_lo[64 * KP];  // [d][n]
    __shared__ __align__(16) __bf16 vtT_hi[64 * KP],  vtT_lo[64 * KP];  // [e][n]

    const int tid  = threadIdx.x;
    const int w    = tid >> 6, lane = tid & 63;
    const int quad = lane >> 4, m = lane & 15;

    for (int s = 0; s < 16; ++s) {
        int flat = s * 256 + tid;          // flat = d*64 + e
        int d = flat >> 6, e = flat & 63;
        float mv = mem[(size_t)h * 4096 + flat];
        __bf16 hi = (__bf16)mv;
        memT_hi[e * KP + d] = hi;
        memT_lo[e * KP + d] = (__bf16)(mv - (float)hi);
    }

    bf16x8 onesv;
    #pragma unroll
    for (int j = 0; j < 8; ++j) onesv[j] = (m == 0) ? (__bf16)1.0f : (__bf16)0.0f;

    f32x4 accM[4];
    #pragma unroll
    for (int t = 0; t < 4; ++t) { f32x4 z = {0.f, 0.f, 0.f, 0.f}; accM[t] = z; }
    __syncthreads();

    for (int sub = 0; sub < 2; ++sub) {
        const int nb = n0 + sub * 64;
        // ---- A1: ek exact f32, split hi/lo into natural + transposed ----
        for (int rr = w; rr < 64; rr += 4) {
            const int n = nb + rr;
            float ekv = eluf(kh[((size_t)bh * N_ + n) * 64 + lane]);
            __bf16 hi = (__bf16)ekv;
            __bf16 lo = (__bf16)(ekv - (float)hi);
            ekn_hi[rr * KP + lane] = hi;
            ekn_lo[rr * KP + lane] = lo;
            ekT_hi[lane * KP + rr] = hi;
            ekT_lo[lane * KP + rr] = lo;
        }
        __syncthreads();

        // ---- A2: km = ek@mem (3-pass) + out_norm (ones column) ----
        f32x4 km[4];
        #pragma unroll
        for (int t = 0; t < 4; ++t) { f32x4 z = {0.f, 0.f, 0.f, 0.f}; km[t] = z; }
        f32x4 nsum = {0.f, 0.f, 0.f, 0.f};
        #pragma unroll
        for (int c2 = 0; c2 < 2; ++c2) {
            bf16x8 Ah = *(const bf16x8*)&ekn_hi[(w * 16 + m) * KP + c2 * 32 + quad * 8];
            bf16x8 Al = *(const bf16x8*)&ekn_lo[(w * 16 + m) * KP + c2 * 32 + quad * 8];
            nsum = __builtin_amdgcn_mfma_f32_16x16x32_bf16(Ah, onesv, nsum, 0, 0, 0);
            nsum = __builtin_amdgcn_mfma_f32_16x16x32_bf16(Al, onesv, nsum, 0, 0, 0);
            #pragma unroll
            for (int et = 0; et < 4; ++et) {
                bf16x8 Bh = *(const bf16x8*)&memT_hi[(et * 16 + m) * KP + c2 * 32 + quad * 8];
                bf16x8 Bl = *(const bf16x8*)&memT_lo[(et * 16 + m) * KP + c2 * 32 + quad * 8];
                km[et] = __builtin_amdgcn_mfma_f32_16x16x32_bf16(Al, Bh, km[et], 0, 0, 0);
                km[et] = __builtin_amdgcn_mfma_f32_16x16x32_bf16(Ah, Bl, km[et], 0, 0, 0);
                km[et] = __builtin_amdgcn_mfma_f32_16x16x32_bf16(Ah, Bh, km[et], 0, 0, 0);
            }
        }
        if (m == 0) {
            #pragma unroll
            for (int r = 0; r < 4; ++r)
                out_norm[(size_t)bh * N_ + nb + w * 16 + quad * 4 + r] = nsum[r];
        }
        float nrmv[4];
        #pragma unroll
        for (int r = 0; r < 4; ++r)
            nrmv[r] = mem_norm[(size_t)h * N_ + nb + w * 16 + quad * 4 + r];
        #pragma unroll
        for (int et = 0; et < 4; ++et) {
            #pragma unroll
            for (int r = 0; r < 4; ++r) {
                const int nl = w * 16 + quad * 4 + r;
                const int e  = et * 16 + m;
                float vh  = (float)vb[((size_t)bh * N_ + nb + nl) * 64 + e];
                float ekv = (float)ekn_hi[nl * KP + e] + (float)ekn_lo[nl * KP + e];
                float vt  = vh - km[et][r] * __builtin_amdgcn_rcpf(ekv * nrmv[r]);
                __bf16 hi = (__bf16)vt;
                vtT_hi[e * KP + nl] = hi;
                vtT_lo[e * KP + nl] = (__bf16)(vt - (float)hi);
            }
        }
        __syncthreads();

        // ---- B: accM += ek^T @ v_term (3-pass MFMA) ----
        #pragma unroll
        for (int c2 = 0; c2 < 2; ++c2) {
            bf16x8 Ah = *(const bf16x8*)&ekT_hi[(w * 16 + m) * KP + c2 * 32 + quad * 8];
            bf16x8 Al = *(const bf16x8*)&ekT_lo[(w * 16 + m) * KP + c2 * 32 + quad * 8];
            #pragma unroll
            for (int et = 0; et < 4; ++et) {
                bf16x8 Bh = *(const bf16x8*)&vtT_hi[(et * 16 + m) * KP + c2 * 32 + quad * 8];
                bf16x8 Bl = *(const bf16x8*)&vtT_lo[(et * 16 + m) * KP + c2 * 32 + quad * 8];
                accM[et] = __builtin_amdgcn_mfma_f32_16x16x32_bf16(Al, Bh, accM[et], 0, 0, 0);
                accM[et] = __builtin_amdgcn_mfma_f32_16x16x32_bf16(Ah, Bl, accM[et], 0, 0, 0);
                accM[et] = __builtin_amdgcn_mfma_f32_16x16x32_bf16(Ah, Bh, accM[et], 0, 0, 0);
            }
        }
        __syncthreads();
    }

    const size_t base = ((size_t)chunk * BH_ + bh) * 4096;
    #pragma unroll
    for (int et = 0; et < 4; ++et)
        #pragma unroll
        for (int r = 0; r < 4; ++r)
            pmem[base + (size_t)(w * 16 + quad * 4 + r) * 64 + et * 16 + m] =
                accM[et][r];
}

// ---- K3g: Gv partials = Wg^T @ vh (unchanged from round-6 PASS) ----
__global__ __launch_bounds__(256) void k_gv(
    const float* __restrict__ Wg, const __bf16* __restrict__ vbT,
    float* __restrict__ pGv)
{
    const int chunk = blockIdx.x;    // 0..15
    const int bh    = blockIdx.y;
    const int n0    = chunk * 128;
    __shared__ __align__(16) __bf16 WgT[64 * 136];   // [d][n], pitch 272B
    const int tid  = threadIdx.x;
    const int w    = tid >> 6, lane = tid & 63;
    const int quad = lane >> 4, m = tid & 15;

    for (int s = 0; s < 8; ++s) {
        int f4 = s * 256 + tid;
        int n = f4 >> 4, dg = (f4 & 15) * 4;
        float4 wv = *(const float4*)&Wg[(size_t)(n0 + n) * 64 + dg];
        WgT[(dg + 0) * 136 + n] = (__bf16)wv.x;
        WgT[(dg + 1) * 136 + n] = (__bf16)wv.y;
        WgT[(dg + 2) * 136 + n] = (__bf16)wv.z;
        WgT[(dg + 3) * 136 + n] = (__bf16)wv.w;
    }
    __syncthreads();

    f32x4 acc[4];
    #pragma unroll
    for (int t = 0; t < 4; ++t) { f32x4 z = {0.f, 0.f, 0.f, 0.f}; acc[t] = z; }
    #pragma unroll
    for (int c = 0; c < 4; ++c) {
        bf16x8 Af = *(const bf16x8*)&WgT[(w * 16 + m) * 136 + c * 32 + quad * 8];
        #pragma unroll
        for (int et = 0; et < 4; ++et) {
            bf16x8 Bf = *(const bf16x8*)&vbT[((size_t)bh * 64 + et * 16 + m) * N_ +
                                             n0 + c * 32 + quad * 8];
            acc[et] = __builtin_amdgcn_mfma_f32_16x16x32_bf16(Af, Bf, acc[et], 0, 0, 0);
        }
    }
    const size_t base = ((size_t)chunk * BH_ + bh) * 4096;
    #pragma unroll
    for (int et = 0; et < 4; ++et)
        #pragma unroll
        for (int r = 0; r < 4; ++r)
            pGv[base + (size_t)(w * 16 + quad * 4 + r) * 64 + et * 16 + m] =
                acc[et][r];
}

// ---------------- K3b: reduce partials (unchanged) ----------------
__global__ __launch_bounds__(256) void k_reduce(
    const float* __restrict__ mem, const float* __restrict__ pmem,
    const float* __restrict__ pGv, float* __restrict__ out_mem, float* __restrict__ Gv)
{
    const int idx = blockIdx.x * 256 + threadIdx.x;
    const int bh = idx >> 12, h = bh & 7, de = idx & 4095;
    float sm = mem[(size_t)h * 4096 + de];
    float sg = 0.0f;
    #pragma unroll
    for (int c = 0; c < 16; ++c) {
        sm += pmem[(size_t)c * 131072 + idx];
        sg += pGv[(size_t)c * 131072 + idx];
    }
    out_mem[idx] = sm;
    Gv[idx] = sg;
}

// ---------- K4: flash attention (round-6 structure; exp2 on pre-scaled kb) ----------
// 256 thr = 4 waves; 128-row blocks; wave owns 32 q-rows (2 strips).
__global__ __launch_bounds__(256, 4) void k_flash(
    const __bf16* __restrict__ qb, const __bf16* __restrict__ kb,
    const __bf16* __restrict__ vbT, const float* __restrict__ mem,
    const float* __restrict__ mem_norm, const float* __restrict__ Gv,
    const float* __restrict__ s_local_p, const float* __restrict__ s_long_p,
    __bf16* __restrict__ o)
{
    const int n0 = blockIdx.x * 128;
    const int bh = blockIdx.y;
    const int h  = bh & 7;
    const __bf16* __restrict__ kbp = kb  + (size_t)bh * N_ * 64;
    const __bf16* __restrict__ vtp = vbT + (size_t)bh * 64 * N_;

    __shared__ __align__(16) __bf16 Kb[64 * KP];    // [kcol][d]; epilogue: MT [e][d]
    __shared__ __align__(16) __bf16 VT[64 * KP];    // [e][n];   epilogue: GT [e][d]
    __shared__ __align__(16) __bf16 Pw[128 * KP];   // [qrow][kcol] per-wave strips
    __shared__ float lsl[128];
    __shared__ float nrm_l[128];

    const int tid  = threadIdx.x;
    const int w    = tid >> 6, lane = tid & 63;
    const int quad = lane >> 4, m = lane & 15;
    const float gl   = 1.0f - 1.0f / (1.0f + __expf(-s_local_p[0]));
    const float sigg = 1.0f / (1.0f + __expf(-s_long_p[0]));

    if (tid < 128) nrm_l[tid] = mem_norm[(size_t)h * N_ + n0 + tid];

    const size_t q0 = ((size_t)bh * N_ + n0 + w * 32 + m) * 64;
    const size_t q1 = q0 + 16 * 64;
    bf16x8 qa00 = *(const bf16x8*)&qb[q0 + quad * 8];
    bf16x8 qa01 = *(const bf16x8*)&qb[q0 + 32 + quad * 8];
    bf16x8 qa10 = *(const bf16x8*)&qb[q1 + quad * 8];
    bf16x8 qa11 = *(const bf16x8*)&qb[q1 + 32 + quad * 8];

    f32x4 O0[4], O1[4];
    #pragma unroll
    for (int t = 0; t < 4; ++t) {
        f32x4 z = {0.f, 0.f, 0.f, 0.f};
        O0[t] = z; O1[t] = z;
    }
    float lsum0 = 0.f, lsum1 = 0.f;
    const int pr0 = w * 32, pr1 = w * 32 + 16;

    const int srow = tid >> 2, scg = (tid & 3) * 16;
    bf16x8 pk0 = *(const bf16x8*)&kbp[(size_t)srow * 64 + scg];
    bf16x8 pk1 = *(const bf16x8*)&kbp[(size_t)srow * 64 + scg + 8];
    bf16x8 pv0 = *(const bf16x8*)&vtp[(size_t)srow * N_ + scg];
    bf16x8 pv1 = *(const bf16x8*)&vtp[(size_t)srow * N_ + scg + 8];

    for (int c = 0; c < 32; ++c) {
        __syncthreads();
        *(bf16x8*)&Kb[srow * KP + scg]     = pk0;
        *(bf16x8*)&Kb[srow * KP + scg + 8] = pk1;
        *(bf16x8*)&VT[srow * KP + scg]     = pv0;
        *(bf16x8*)&VT[srow * KP + scg + 8] = pv1;
        __syncthreads();
        if (c + 1 < 32) {
            const size_t kn = (size_t)((c + 1) * 64 + srow) * 64 + scg;
            const size_t vn = (size_t)srow * N_ + (c + 1) * 64 + scg;
            pk0 = *(const bf16x8*)&kbp[kn];
            pk1 = *(const bf16x8*)&kbp[kn + 8];
            pv0 = *(const bf16x8*)&vtp[vn];
            pv1 = *(const bf16x8*)&vtp[vn + 8];
        }

        // ---- S^T = K' Q^T (K pre-scaled) ----
        f32x4 s0[4], s1[4];
        #pragma unroll
        for (int t = 0; t < 4; ++t) {
            bf16x8 ka0 = *(const bf16x8*)&Kb[(t * 16 + m) * KP + quad * 8];
            bf16x8 ka1 = *(const bf16x8*)&Kb[(t * 16 + m) * KP + 32 + quad * 8];
            f32x4 z = {0.f, 0.f, 0.f, 0.f};
            z = __builtin_amdgcn_mfma_f32_16x16x32_bf16(ka0, qa00, z, 0, 0, 0);
            s0[t] = __builtin_amdgcn_mfma_f32_16x16x32_bf16(ka1, qa01, z, 0, 0, 0);
            f32x4 z2 = {0.f, 0.f, 0.f, 0.f};
            z2 = __builtin_amdgcn_mfma_f32_16x16x32_bf16(ka0, qa10, z2, 0, 0, 0);
            s1[t] = __builtin_amdgcn_mfma_f32_16x16x32_bf16(ka1, qa11, z2, 0, 0, 0);
        }

        // ---- p = exp2(s) (scale pre-folded into kb); lsum; P -> strips ----
        #pragma unroll
        for (int t = 0; t < 4; ++t) {
            float p0 = exp2f(s0[t][0]), p1 = exp2f(s0[t][1]);
            float p2 = exp2f(s0[t][2]), p3 = exp2f(s0[t][3]);
            lsum0 += p0 + p1 + p2 + p3;
            bf16x4 pk = {(__bf16)p0, (__bf16)p1, (__bf16)p2, (__bf16)p3};
            *(bf16x4*)&Pw[(pr0 + m) * KP + t * 16 + quad * 4] = pk;
            float r0 = exp2f(s1[t][0]), r1 = exp2f(s1[t][1]);
            float r2 = exp2f(s1[t][2]), r3 = exp2f(s1[t][3]);
            lsum1 += r0 + r1 + r2 + r3;
            bf16x4 rk = {(__bf16)r0, (__bf16)r1, (__bf16)r2, (__bf16)r3};
            *(bf16x4*)&Pw[(pr1 + m) * KP + t * 16 + quad * 4] = rk;
        }
        asm volatile("s_waitcnt lgkmcnt(0)" ::: "memory");

        // ---- O += P V ----
        #pragma unroll
        for (int c2 = 0; c2 < 2; ++c2) {
            bf16x8 pa0 = *(const bf16x8*)&Pw[(pr0 + m) * KP + c2 * 32 + quad * 8];
            bf16x8 pa1 = *(const bf16x8*)&Pw[(pr1 + m) * KP + c2 * 32 + quad * 8];
            #pragma unroll
            for (int t = 0; t < 4; ++t) {
                bf16x8 vv = *(const bf16x8*)&VT[(t * 16 + m) * KP + c2 * 32 + quad * 8];
                O0[t] = __builtin_amdgcn_mfma_f32_16x16x32_bf16(pa0, vv, O0[t], 0, 0, 0);
                O1[t] = __builtin_amdgcn_mfma_f32_16x16x32_bf16(pa1, vv, O1[t], 0, 0, 0);
            }
        }
    }

    lsum0 += __shfl_xor(lsum0, 16, 64); lsum0 += __shfl_xor(lsum0, 32, 64);
    lsum1 += __shfl_xor(lsum1, 16, 64); lsum1 += __shfl_xor(lsum1, 32, 64);
    if (lane < 16) { lsl[pr0 + lane] = lsum0; lsl[pr1 + lane] = lsum1; }

    __syncthreads();
    for (int s2 = 0; s2 < 16; ++s2) {
        int flat = s2 * 256 + tid;          // flat = d*64 + e
        int d = flat >> 6, e = flat & 63;
        Kb[e * KP + d] = (__bf16)mem[(size_t)h * 4096 + flat];
        VT[e * KP + d] = (__bf16)Gv[(size_t)bh * 4096 + flat];
    }
    __syncthreads();

    __bf16* op = o + ((size_t)bh * N_ + n0) * 64;
    #pragma unroll
    for (int s = 0; s < 2; ++s) {
        const int prs = w * 32 + s * 16;
        bf16x8 ea0, ea1;
        #pragma unroll
        for (int j = 0; j < 8; ++j) {
            ea0[j] = (__bf16)eluf((float)(s == 0 ? qa00[j] : qa10[j]));
            ea1[j] = (__bf16)eluf((float)(s == 0 ? qa01[j] : qa11[j]));
        }
        f32x4 num[4];
        #pragma unroll
        for (int t = 0; t < 4; ++t) {
            bf16x8 b0 = *(const bf16x8*)&Kb[(t * 16 + m) * KP + quad * 8];
            bf16x8 b1 = *(const bf16x8*)&Kb[(t * 16 + m) * KP + 32 + quad * 8];
            f32x4 z = {0.f, 0.f, 0.f, 0.f};
            z = __builtin_amdgcn_mfma_f32_16x16x32_bf16(ea0, b0, z, 0, 0, 0);
            num[t] = __builtin_amdgcn_mfma_f32_16x16x32_bf16(ea1, b1, z, 0, 0, 0);
        }
        *(bf16x8*)&Pw[(prs + m) * KP + quad * 8]      = ea0;
        *(bf16x8*)&Pw[(prs + m) * KP + 32 + quad * 8] = ea1;
        asm volatile("s_waitcnt lgkmcnt(0)" ::: "memory");
        float mq[4][4];
        #pragma unroll
        for (int t = 0; t < 4; ++t)
            #pragma unroll
            for (int r = 0; r < 4; ++r) {
                float eqv = (float)Pw[(prs + quad * 4 + r) * KP + t * 16 + m];
                mq[t][r] = num[t][r] / (eqv * nrm_l[prs + quad * 4 + r]);
            }
        #pragma unroll
        for (int t = 0; t < 4; ++t)
            #pragma unroll
            for (int r = 0; r < 4; ++r)
                Pw[(prs + quad * 4 + r) * KP + t * 16 + m] = (__bf16)mq[t][r];
        asm volatile("s_waitcnt lgkmcnt(0)" ::: "memory");
        bf16x8 ma0 = *(const bf16x8*)&Pw[(prs + m) * KP + quad * 8];
        bf16x8 ma1 = *(const bf16x8*)&Pw[(prs + m) * KP + 32 + quad * 8];

        #pragma unroll
        for (int t = 0; t < 4; ++t) {
            bf16x8 g0 = *(const bf16x8*)&VT[(t * 16 + m) * KP + quad * 8];
            bf16x8 g1 = *(const bf16x8*)&VT[(t * 16 + m) * KP + 32 + quad * 8];
            f32x4 z = {0.f, 0.f, 0.f, 0.f};
            z = __builtin_amdgcn_mfma_f32_16x16x32_bf16(ma0, g0, z, 0, 0, 0);
            f32x4 o2 = __builtin_amdgcn_mfma_f32_16x16x32_bf16(ma1, g1, z, 0, 0, 0);
            #pragma unroll
            for (int r = 0; r < 4; ++r) {
                const int qr = prs + quad * 4 + r;
                float val = ((s == 0) ? O0[t][r] : O1[t][r]) * (gl / lsl[qr])
                            + sigg * o2[r];
                op[(size_t)qr * 64 + t * 16 + m] = (__bf16)val;
            }
        }
    }
}

// ---------------- K5: output projection on MFMA (unchanged) ----------------
__global__ __launch_bounds__(256) void k_outproj(
    const __bf16* __restrict__ o, const float* __restrict__ Wo,
    const float* __restrict__ bo, float* __restrict__ out)
{
    const int row0 = blockIdx.x * 64;      // over B*N
    const int b = row0 >> 11, nb = row0 & 2047;
    __shared__ __align__(16) __bf16 WoS[64 * 40];   // [dout][k] per 32-k block
    const int tid  = threadIdx.x;
    const int w    = tid >> 6, lane = tid & 63;
    const int quad = lane >> 4, m = lane & 15;

    f32x4 acc[4];
    #pragma unroll
    for (int t = 0; t < 4; ++t) { f32x4 z = {0.f, 0.f, 0.f, 0.f}; acc[t] = z; }

    for (int kbk = 0; kbk < 16; ++kbk) {
        for (int s2 = 0; s2 < 8; ++s2) {
            int flat = s2 * 256 + tid;      // flat = n*32 + kk
            int n = flat >> 5, kk = flat & 31;
            WoS[n * 40 + kk] = (__bf16)Wo[(size_t)n * 512 + kbk * 32 + kk];
        }
        __syncthreads();
        const int hc = kbk >> 1;
        size_t arow = (((size_t)b * H_ + hc) * N_ + nb + w * 16 + m);
        bf16x8 af = *(const bf16x8*)&o[arow * 64 + (kbk & 1) * 32 + quad * 8];
        #pragma unroll
        for (int t = 0; t < 4; ++t) {
            bf16x8 bf_ = *(const bf16x8*)&WoS[(t * 16 + m) * 40 + quad * 8];
            acc[t] = __builtin_amdgcn_mfma_f32_16x16x32_bf16(af, bf_, acc[t], 0, 0, 0);
        }
        __syncthreads();
    }
    #pragma unroll
    for (int t = 0; t < 4; ++t) {
        float bias = bo[t * 16 + m];
        #pragma unroll
        for (int r = 0; r < 4; ++r)
            out[(size_t)(row0 + w * 16 + quad * 4 + r) * 64 + t * 16 + m] =
                acc[t][r] + bias;
    }
}

extern "C" void kernel_launch(void* const* d_in, const int* in_sizes, int n_in,
                              void* d_out, int out_size, void* d_ws, size_t ws_size,
                              hipStream_t stream)
{
    const float* q        = (const float*)d_in[0];
    const float* k        = (const float*)d_in[1];
    const float* v        = (const float*)d_in[2];
    const float* Wq       = (const float*)d_in[3];
    const float* Wk       = (const float*)d_in[4];
    const float* Wv       = (const float*)d_in[5];
    const float* Wo       = (const float*)d_in[6];
    const float* bo       = (const float*)d_in[7];
    const float* Wg       = (const float*)d_in[8];
    const float* s_local  = (const float*)d_in[9];
    const float* s_long   = (const float*)d_in[10];
    const float* mem      = (const float*)d_in[11];
    const float* mem_norm = (const float*)d_in[12];

    float* ws = (float*)d_ws;
    float*  kh  = ws;
    __bf16* qb  = (__bf16*)(ws + 4194304);
    __bf16* kb  = (__bf16*)(ws + 6291456);
    __bf16* vb  = (__bf16*)(ws + 8388608);
    __bf16* vbT = (__bf16*)(ws + 10485760);
    float*  Gv  = ws + 12582912;
    float*  pm  = ws + 12713984;
    float*  pg  = ws + 14811136;
    __bf16* o   = (__bf16*)(ws + 12713984);   // aliases pm (dead after k_reduce)

    float* out      = (float*)d_out;
    float* out_mem  = out + 524288;
    float* out_norm = out + 655360;

    k_proj   <<<dim3(128, 8, 3), 256, 0, stream>>>(q, k, v, Wq, Wk, Wv,
                                                   qb, kh, kb, vb, vbT);
    k_memacc <<<dim3(16, 32),    256, 0, stream>>>(kh, vb, mem, mem_norm,
                                                   pm, out_norm);
    k_gv     <<<dim3(16, 32),    256, 0, stream>>>(Wg, vbT, pg);
    k_reduce <<<dim3(512),       256, 0, stream>>>(mem, pm, pg, out_mem, Gv);
    k_flash  <<<dim3(16, 32),    256, 0, stream>>>(qb, kb, vbT, mem, mem_norm, Gv,
                                                   s_local, s_long, o);
    k_outproj<<<dim3(128),       256, 0, stream>>>(o, Wo, bo, out);
}

// Round 11
// 203.468 us; speedup vs baseline: 1.1651x; 1.0686x over previous
//
#include <hip/hip_runtime.h>
#include <math.h>

// InfiniAttention fused forward, MI355X round 11.
// B=4, N=2048, DIM=64, H=8, DH=64.
// Round-11 = round-10 (best: 217.4 us) with ONE change: k_flash softmax uses
// __builtin_amdgcn_exp2f (bare v_exp_f32) instead of libm exp2f. r10's
// counters showed VALUBusy UP 40->48 after deleting muls -- exp2f is the
// OCML edge-case-correct call (~6 extra VALU/call); __expf/__builtin map to
// the raw instruction. 32 calls/thread/iter made this the k_flash 71->82 us
// regression. Everything else byte-identical to the round-10 PASS.
//
// Workspace (floats, 16908288 total = 67,633,152 B):
//   kh   @ 0         f32  4194304
//   qb   @ 4194304   bf16 [bh][n][d]
//   kb   @ 6291456   bf16 [bh][n][d]  (pre-scaled by 0.1803...)
//   vb   @ 8388608   bf16 [bh][n][d]
//   vbT  @ 10485760  bf16 [bh][e][n]
//   Gv   @ 12582912  f32  131072  [bh][d][e]
//   pm   @ 12713984  f32  2097152 (16 chunks)  <- o bf16 aliases pm
//   pg   @ 14811136  f32  2097152

#define B_   4
#define N_   2048
#define H_   8
#define BH_  32
#define KP   72      // bf16 LDS pitch (144 B)
#define SCLK 0.18033688f   // 0.125 * log2(e), folded into kb

typedef __bf16 bf16x8 __attribute__((ext_vector_type(8)));
typedef __bf16 bf16x4 __attribute__((ext_vector_type(4)));
typedef float  f32x4  __attribute__((ext_vector_type(4)));

__device__ __forceinline__ float eluf(float x) {
    return x > 0.0f ? x : expm1f(x);   // expm1 critical near 0
}

__device__ __forceinline__ float fexp2(float x) {
    return __builtin_amdgcn_exp2f(x);  // bare v_exp_f32 (inputs in normal range)
}

// ---------------- K2: head projections -----------------
// which==0 (q), which==1 (k): exact sequential f32 FMA chain (k bit-matched
// to np sgemm; q needs relative accuracy for tiny elu(q) divisors).
// which==2 (v): bf16 MFMA, no f32 staging (loose consumers only).
__global__ __launch_bounds__(256) void k_proj(
    const float* __restrict__ q, const float* __restrict__ k, const float* __restrict__ v,
    const float* __restrict__ Wq, const float* __restrict__ Wk, const float* __restrict__ Wv,
    __bf16* __restrict__ qb, float* __restrict__ kh, __bf16* __restrict__ kb,
    __bf16* __restrict__ vb, __bf16* __restrict__ vbT)
{
    const int which = blockIdx.z;
    const int h    = blockIdx.y;
    const int row0 = blockIdx.x * 64;   // over B*N = 8192
    const int tid  = threadIdx.x;
    const int b = row0 >> 11, nb = row0 & 2047;

    __shared__ __align__(16) float  AsT[64][68];   // [dim][row] (q/k path)
    __shared__ __align__(16) float  WsT[64][68];   // [dim][col] (q/k path)
    __shared__ __align__(16) __bf16 Cs[64 * 72];   // C bounce (v path)

    if (which == 2) {
        // ---- v: bf16 MFMA ----
        const int w = tid >> 6, lane = tid & 63;
        const int quad = lane >> 4, m = lane & 15;
        const float* ar = v + (size_t)(row0 + w * 16 + m) * 64;
        bf16x8 a0, a1;
        #pragma unroll
        for (int j = 0; j < 8; ++j) {
            a0[j] = (__bf16)ar[quad * 8 + j];
            a1[j] = (__bf16)ar[32 + quad * 8 + j];
        }
        f32x4 acc[4];
        #pragma unroll
        for (int t = 0; t < 4; ++t) {
            const float* wr = Wv + (size_t)(h * 64 + t * 16 + m) * 64;
            bf16x8 b0, b1;
            #pragma unroll
            for (int j = 0; j < 8; ++j) {
                b0[j] = (__bf16)wr[quad * 8 + j];
                b1[j] = (__bf16)wr[32 + quad * 8 + j];
            }
            f32x4 z = {0.f, 0.f, 0.f, 0.f};
            z = __builtin_amdgcn_mfma_f32_16x16x32_bf16(a0, b0, z, 0, 0, 0);
            acc[t] = __builtin_amdgcn_mfma_f32_16x16x32_bf16(a1, b1, z, 0, 0, 0);
        }
        #pragma unroll
        for (int t = 0; t < 4; ++t)
            #pragma unroll
            for (int r = 0; r < 4; ++r)
                Cs[(w * 16 + quad * 4 + r) * 72 + t * 16 + m] = (__bf16)acc[t][r];
        __syncthreads();
        // row-major -> vb
        const int rr = tid >> 2, csg = (tid & 3) * 16;
        bf16x8 r0 = *(const bf16x8*)&Cs[rr * 72 + csg];
        bf16x8 r1 = *(const bf16x8*)&Cs[rr * 72 + csg + 8];
        size_t gb = ((((size_t)b * H_ + h) * N_ + nb + rr) << 6) + csg;
        *(bf16x8*)&vb[gb]     = r0;
        *(bf16x8*)&vb[gb + 8] = r1;
        // col-major -> vbT
        const int e = tid >> 2, ns = (tid & 3) * 16;
        bf16x8 t0, t1;
        #pragma unroll
        for (int j = 0; j < 8; ++j) {
            t0[j] = Cs[(ns + j) * 72 + e];
            t1[j] = Cs[(ns + 8 + j) * 72 + e];
        }
        size_t base = (((size_t)b * H_ + h) * 64 + e) * (size_t)N_ + nb + ns;
        *(bf16x8*)&vbT[base]     = t0;
        *(bf16x8*)&vbT[base + 8] = t1;
        return;
    }

    // ---- q / k: exact f32 chain (byte-identical math to round-2..10 PASS) ----
    const float* __restrict__ src = (which == 0) ? q : k;
    const float* __restrict__ W   = (which == 0) ? Wq : Wk;
    for (int s = 0; s < 16; ++s) {
        int flat = s * 256 + tid;
        int r = flat >> 6, d = flat & 63;
        AsT[d][r] = src[(size_t)(row0 + r) * 64 + d];
        WsT[d][r] = W[(size_t)(h * 64 + r) * 64 + d];
    }
    __syncthreads();

    const int ty = tid >> 4, tx = tid & 15;
    float acc[4][4];
    #pragma unroll
    for (int i = 0; i < 4; ++i)
        #pragma unroll
        for (int j = 0; j < 4; ++j) acc[i][j] = 0.0f;
    for (int kd = 0; kd < 64; ++kd) {
        float4 a4 = *(const float4*)&AsT[kd][ty * 4];
        float4 w4 = *(const float4*)&WsT[kd][tx * 4];
        float a[4] = {a4.x, a4.y, a4.z, a4.w};
        float w[4] = {w4.x, w4.y, w4.z, w4.w};
        #pragma unroll
        for (int i = 0; i < 4; ++i)
            #pragma unroll
            for (int j = 0; j < 4; ++j) acc[i][j] = fmaf(a[i], w[j], acc[i][j]);
    }

    if (which == 0) {
        #pragma unroll
        for (int i = 0; i < 4; ++i) {
            size_t idx = ((((size_t)b * H_ + h) * N_ + nb + ty * 4 + i) << 6) + tx * 4;
            bf16x4 o4 = {(__bf16)acc[i][0], (__bf16)acc[i][1],
                         (__bf16)acc[i][2], (__bf16)acc[i][3]};
            *(bf16x4*)&qb[idx] = o4;
        }
    } else {
        #pragma unroll
        for (int i = 0; i < 4; ++i) {
            size_t idx = ((((size_t)b * H_ + h) * N_ + nb + ty * 4 + i) << 6) + tx * 4;
            *(float4*)&kh[idx] = make_float4(acc[i][0], acc[i][1], acc[i][2], acc[i][3]);
            bf16x4 o4 = {(__bf16)(acc[i][0] * SCLK), (__bf16)(acc[i][1] * SCLK),
                         (__bf16)(acc[i][2] * SCLK), (__bf16)(acc[i][3] * SCLK)};
            *(bf16x4*)&kb[idx] = o4;
        }
    }
}

// ---- K3: memory-update on split-bf16 MFMA (unchanged from round-10 PASS) ----
__global__ __launch_bounds__(256) void k_memacc(
    const float* __restrict__ kh, const __bf16* __restrict__ vb,
    const float* __restrict__ mem, const float* __restrict__ mem_norm,
    float* __restrict__ pmem, float* __restrict__ out_norm)
{
    const int chunk = blockIdx.x;    // 0..15
    const int bh    = blockIdx.y;
    const int h     = bh & 7;
    const int n0    = chunk * 128;

    __shared__ __align__(16) __bf16 memT_hi[64 * KP], memT_lo[64 * KP]; // [e][d]
    __shared__ __align__(16) __bf16 ekn_hi[64 * KP],  ekn_lo[64 * KP];  // [n][d]
    __shared__ __align__(16) __bf16 ekT_hi[64 * KP],  ekT_lo[64 * KP];  // [d][n]
    __shared__ __align__(16) __bf16 vtT_hi[64 * KP],  vtT_lo[64 * KP];  // [e][n]

    const int tid  = threadIdx.x;
    const int w    = tid >> 6, lane = tid & 63;
    const int quad = lane >> 4, m = lane & 15;

    for (int s = 0; s < 16; ++s) {
        int flat = s * 256 + tid;          // flat = d*64 + e
        int d = flat >> 6, e = flat & 63;
        float mv = mem[(size_t)h * 4096 + flat];
        __bf16 hi = (__bf16)mv;
        memT_hi[e * KP + d] = hi;
        memT_lo[e * KP + d] = (__bf16)(mv - (float)hi);
    }

    bf16x8 onesv;
    #pragma unroll
    for (int j = 0; j < 8; ++j) onesv[j] = (m == 0) ? (__bf16)1.0f : (__bf16)0.0f;

    f32x4 accM[4];
    #pragma unroll
    for (int t = 0; t < 4; ++t) { f32x4 z = {0.f, 0.f, 0.f, 0.f}; accM[t] = z; }
    __syncthreads();

    for (int sub = 0; sub < 2; ++sub) {
        const int nb = n0 + sub * 64;
        // ---- A1: ek exact f32, split hi/lo into natural + transposed ----
        for (int rr = w; rr < 64; rr += 4) {
            const int n = nb + rr;
            float ekv = eluf(kh[((size_t)bh * N_ + n) * 64 + lane]);
            __bf16 hi = (__bf16)ekv;
            __bf16 lo = (__bf16)(ekv - (float)hi);
            ekn_hi[rr * KP + lane] = hi;
            ekn_lo[rr * KP + lane] = lo;
            ekT_hi[lane * KP + rr] = hi;
            ekT_lo[lane * KP + rr] = lo;
        }
        __syncthreads();

        // ---- A2: km = ek@mem (3-pass) + out_norm (ones column) ----
        f32x4 km[4];
        #pragma unroll
        for (int t = 0; t < 4; ++t) { f32x4 z = {0.f, 0.f, 0.f, 0.f}; km[t] = z; }
        f32x4 nsum = {0.f, 0.f, 0.f, 0.f};
        #pragma unroll
        for (int c2 = 0; c2 < 2; ++c2) {
            bf16x8 Ah = *(const bf16x8*)&ekn_hi[(w * 16 + m) * KP + c2 * 32 + quad * 8];
            bf16x8 Al = *(const bf16x8*)&ekn_lo[(w * 16 + m) * KP + c2 * 32 + quad * 8];
            nsum = __builtin_amdgcn_mfma_f32_16x16x32_bf16(Ah, onesv, nsum, 0, 0, 0);
            nsum = __builtin_amdgcn_mfma_f32_16x16x32_bf16(Al, onesv, nsum, 0, 0, 0);
            #pragma unroll
            for (int et = 0; et < 4; ++et) {
                bf16x8 Bh = *(const bf16x8*)&memT_hi[(et * 16 + m) * KP + c2 * 32 + quad * 8];
                bf16x8 Bl = *(const bf16x8*)&memT_lo[(et * 16 + m) * KP + c2 * 32 + quad * 8];
                km[et] = __builtin_amdgcn_mfma_f32_16x16x32_bf16(Al, Bh, km[et], 0, 0, 0);
                km[et] = __builtin_amdgcn_mfma_f32_16x16x32_bf16(Ah, Bl, km[et], 0, 0, 0);
                km[et] = __builtin_amdgcn_mfma_f32_16x16x32_bf16(Ah, Bh, km[et], 0, 0, 0);
            }
        }
        if (m == 0) {
            #pragma unroll
            for (int r = 0; r < 4; ++r)
                out_norm[(size_t)bh * N_ + nb + w * 16 + quad * 4 + r] = nsum[r];
        }
        float nrmv[4];
        #pragma unroll
        for (int r = 0; r < 4; ++r)
            nrmv[r] = mem_norm[(size_t)h * N_ + nb + w * 16 + quad * 4 + r];
        #pragma unroll
        for (int et = 0; et < 4; ++et) {
            #pragma unroll
            for (int r = 0; r < 4; ++r) {
                const int nl = w * 16 + quad * 4 + r;
                const int e  = et * 16 + m;
                float vh  = (float)vb[((size_t)bh * N_ + nb + nl) * 64 + e];
                float ekv = (float)ekn_hi[nl * KP + e] + (float)ekn_lo[nl * KP + e];
                float vt  = vh - km[et][r] * __builtin_amdgcn_rcpf(ekv * nrmv[r]);
                __bf16 hi = (__bf16)vt;
                vtT_hi[e * KP + nl] = hi;
                vtT_lo[e * KP + nl] = (__bf16)(vt - (float)hi);
            }
        }
        __syncthreads();

        // ---- B: accM += ek^T @ v_term (3-pass MFMA) ----
        #pragma unroll
        for (int c2 = 0; c2 < 2; ++c2) {
            bf16x8 Ah = *(const bf16x8*)&ekT_hi[(w * 16 + m) * KP + c2 * 32 + quad * 8];
            bf16x8 Al = *(const bf16x8*)&ekT_lo[(w * 16 + m) * KP + c2 * 32 + quad * 8];
            #pragma unroll
            for (int et = 0; et < 4; ++et) {
                bf16x8 Bh = *(const bf16x8*)&vtT_hi[(et * 16 + m) * KP + c2 * 32 + quad * 8];
                bf16x8 Bl = *(const bf16x8*)&vtT_lo[(et * 16 + m) * KP + c2 * 32 + quad * 8];
                accM[et] = __builtin_amdgcn_mfma_f32_16x16x32_bf16(Al, Bh, accM[et], 0, 0, 0);
                accM[et] = __builtin_amdgcn_mfma_f32_16x16x32_bf16(Ah, Bl, accM[et], 0, 0, 0);
                accM[et] = __builtin_amdgcn_mfma_f32_16x16x32_bf16(Ah, Bh, accM[et], 0, 0, 0);
            }
        }
        __syncthreads();
    }

    const size_t base = ((size_t)chunk * BH_ + bh) * 4096;
    #pragma unroll
    for (int et = 0; et < 4; ++et)
        #pragma unroll
        for (int r = 0; r < 4; ++r)
            pmem[base + (size_t)(w * 16 + quad * 4 + r) * 64 + et * 16 + m] =
                accM[et][r];
}

// ---- K3g: Gv partials = Wg^T @ vh (unchanged from round-6 PASS) ----
__global__ __launch_bounds__(256) void k_gv(
    const float* __restrict__ Wg, const __bf16* __restrict__ vbT,
    float* __restrict__ pGv)
{
    const int chunk = blockIdx.x;    // 0..15
    const int bh    = blockIdx.y;
    const int n0    = chunk * 128;
    __shared__ __align__(16) __bf16 WgT[64 * 136];   // [d][n], pitch 272B
    const int tid  = threadIdx.x;
    const int w    = tid >> 6, lane = tid & 63;
    const int quad = lane >> 4, m = tid & 15;

    for (int s = 0; s < 8; ++s) {
        int f4 = s * 256 + tid;
        int n = f4 >> 4, dg = (f4 & 15) * 4;
        float4 wv = *(const float4*)&Wg[(size_t)(n0 + n) * 64 + dg];
        WgT[(dg + 0) * 136 + n] = (__bf16)wv.x;
        WgT[(dg + 1) * 136 + n] = (__bf16)wv.y;
        WgT[(dg + 2) * 136 + n] = (__bf16)wv.z;
        WgT[(dg + 3) * 136 + n] = (__bf16)wv.w;
    }
    __syncthreads();

    f32x4 acc[4];
    #pragma unroll
    for (int t = 0; t < 4; ++t) { f32x4 z = {0.f, 0.f, 0.f, 0.f}; acc[t] = z; }
    #pragma unroll
    for (int c = 0; c < 4; ++c) {
        bf16x8 Af = *(const bf16x8*)&WgT[(w * 16 + m) * 136 + c * 32 + quad * 8];
        #pragma unroll
        for (int et = 0; et < 4; ++et) {
            bf16x8 Bf = *(const bf16x8*)&vbT[((size_t)bh * 64 + et * 16 + m) * N_ +
                                             n0 + c * 32 + quad * 8];
            acc[et] = __builtin_amdgcn_mfma_f32_16x16x32_bf16(Af, Bf, acc[et], 0, 0, 0);
        }
    }
    const size_t base = ((size_t)chunk * BH_ + bh) * 4096;
    #pragma unroll
    for (int et = 0; et < 4; ++et)
        #pragma unroll
        for (int r = 0; r < 4; ++r)
            pGv[base + (size_t)(w * 16 + quad * 4 + r) * 64 + et * 16 + m] =
                acc[et][r];
}

// ---------------- K3b: reduce partials (unchanged) ----------------
__global__ __launch_bounds__(256) void k_reduce(
    const float* __restrict__ mem, const float* __restrict__ pmem,
    const float* __restrict__ pGv, float* __restrict__ out_mem, float* __restrict__ Gv)
{
    const int idx = blockIdx.x * 256 + threadIdx.x;
    const int bh = idx >> 12, h = bh & 7, de = idx & 4095;
    float sm = mem[(size_t)h * 4096 + de];
    float sg = 0.0f;
    #pragma unroll
    for (int c = 0; c < 16; ++c) {
        sm += pmem[(size_t)c * 131072 + idx];
        sg += pGv[(size_t)c * 131072 + idx];
    }
    out_mem[idx] = sm;
    Gv[idx] = sg;
}

// ---------- K4: flash attention (round-6 structure; raw v_exp_f32) ----------
// 256 thr = 4 waves; 128-row blocks; wave owns 32 q-rows (2 strips).
__global__ __launch_bounds__(256, 4) void k_flash(
    const __bf16* __restrict__ qb, const __bf16* __restrict__ kb,
    const __bf16* __restrict__ vbT, const float* __restrict__ mem,
    const float* __restrict__ mem_norm, const float* __restrict__ Gv,
    const float* __restrict__ s_local_p, const float* __restrict__ s_long_p,
    __bf16* __restrict__ o)
{
    const int n0 = blockIdx.x * 128;
    const int bh = blockIdx.y;
    const int h  = bh & 7;
    const __bf16* __restrict__ kbp = kb  + (size_t)bh * N_ * 64;
    const __bf16* __restrict__ vtp = vbT + (size_t)bh * 64 * N_;

    __shared__ __align__(16) __bf16 Kb[64 * KP];    // [kcol][d]; epilogue: MT [e][d]
    __shared__ __align__(16) __bf16 VT[64 * KP];    // [e][n];   epilogue: GT [e][d]
    __shared__ __align__(16) __bf16 Pw[128 * KP];   // [qrow][kcol] per-wave strips
    __shared__ float lsl[128];
    __shared__ float nrm_l[128];

    const int tid  = threadIdx.x;
    const int w    = tid >> 6, lane = tid & 63;
    const int quad = lane >> 4, m = lane & 15;
    const float gl   = 1.0f - 1.0f / (1.0f + __expf(-s_local_p[0]));
    const float sigg = 1.0f / (1.0f + __expf(-s_long_p[0]));

    if (tid < 128) nrm_l[tid] = mem_norm[(size_t)h * N_ + n0 + tid];

    const size_t q0 = ((size_t)bh * N_ + n0 + w * 32 + m) * 64;
    const size_t q1 = q0 + 16 * 64;
    bf16x8 qa00 = *(const bf16x8*)&qb[q0 + quad * 8];
    bf16x8 qa01 = *(const bf16x8*)&qb[q0 + 32 + quad * 8];
    bf16x8 qa10 = *(const bf16x8*)&qb[q1 + quad * 8];
    bf16x8 qa11 = *(const bf16x8*)&qb[q1 + 32 + quad * 8];

    f32x4 O0[4], O1[4];
    #pragma unroll
    for (int t = 0; t < 4; ++t) {
        f32x4 z = {0.f, 0.f, 0.f, 0.f};
        O0[t] = z; O1[t] = z;
    }
    float lsum0 = 0.f, lsum1 = 0.f;
    const int pr0 = w * 32, pr1 = w * 32 + 16;

    const int srow = tid >> 2, scg = (tid & 3) * 16;
    bf16x8 pk0 = *(const bf16x8*)&kbp[(size_t)srow * 64 + scg];
    bf16x8 pk1 = *(const bf16x8*)&kbp[(size_t)srow * 64 + scg + 8];
    bf16x8 pv0 = *(const bf16x8*)&vtp[(size_t)srow * N_ + scg];
    bf16x8 pv1 = *(const bf16x8*)&vtp[(size_t)srow * N_ + scg + 8];

    for (int c = 0; c < 32; ++c) {
        __syncthreads();
        *(bf16x8*)&Kb[srow * KP + scg]     = pk0;
        *(bf16x8*)&Kb[srow * KP + scg + 8] = pk1;
        *(bf16x8*)&VT[srow * KP + scg]     = pv0;
        *(bf16x8*)&VT[srow * KP + scg + 8] = pv1;
        __syncthreads();
        if (c + 1 < 32) {
            const size_t kn = (size_t)((c + 1) * 64 + srow) * 64 + scg;
            const size_t vn = (size_t)srow * N_ + (c + 1) * 64 + scg;
            pk0 = *(const bf16x8*)&kbp[kn];
            pk1 = *(const bf16x8*)&kbp[kn + 8];
            pv0 = *(const bf16x8*)&vtp[vn];
            pv1 = *(const bf16x8*)&vtp[vn + 8];
        }

        // ---- S^T = K' Q^T (K pre-scaled by 0.125*log2e) ----
        f32x4 s0[4], s1[4];
        #pragma unroll
        for (int t = 0; t < 4; ++t) {
            bf16x8 ka0 = *(const bf16x8*)&Kb[(t * 16 + m) * KP + quad * 8];
            bf16x8 ka1 = *(const bf16x8*)&Kb[(t * 16 + m) * KP + 32 + quad * 8];
            f32x4 z = {0.f, 0.f, 0.f, 0.f};
            z = __builtin_amdgcn_mfma_f32_16x16x32_bf16(ka0, qa00, z, 0, 0, 0);
            s0[t] = __builtin_amdgcn_mfma_f32_16x16x32_bf16(ka1, qa01, z, 0, 0, 0);
            f32x4 z2 = {0.f, 0.f, 0.f, 0.f};
            z2 = __builtin_amdgcn_mfma_f32_16x16x32_bf16(ka0, qa10, z2, 0, 0, 0);
            s1[t] = __builtin_amdgcn_mfma_f32_16x16x32_bf16(ka1, qa11, z2, 0, 0, 0);
        }

        // ---- p = v_exp_f32(s); lsum; P -> strips (b64 writes) ----
        #pragma unroll
        for (int t = 0; t < 4; ++t) {
            float p0 = fexp2(s0[t][0]), p1 = fexp2(s0[t][1]);
            float p2 = fexp2(s0[t][2]), p3 = fexp2(s0[t][3]);
            lsum0 += p0 + p1 + p2 + p3;
            bf16x4 pk = {(__bf16)p0, (__bf16)p1, (__bf16)p2, (__bf16)p3};
            *(bf16x4*)&Pw[(pr0 + m) * KP + t * 16 + quad * 4] = pk;
            float r0 = fexp2(s1[t][0]), r1 = fexp2(s1[t][1]);
            float r2 = fexp2(s1[t][2]), r3 = fexp2(s1[t][3]);
            lsum1 += r0 + r1 + r2 + r3;
            bf16x4 rk = {(__bf16)r0, (__bf16)r1, (__bf16)r2, (__bf16)r3};
            *(bf16x4*)&Pw[(pr1 + m) * KP + t * 16 + quad * 4] = rk;
        }
        asm volatile("s_waitcnt lgkmcnt(0)" ::: "memory");

        // ---- O += P V ----
        #pragma unroll
        for (int c2 = 0; c2 < 2; ++c2) {
            bf16x8 pa0 = *(const bf16x8*)&Pw[(pr0 + m) * KP + c2 * 32 + quad * 8];
            bf16x8 pa1 = *(const bf16x8*)&Pw[(pr1 + m) * KP + c2 * 32 + quad * 8];
            #pragma unroll
            for (int t = 0; t < 4; ++t) {
                bf16x8 vv = *(const bf16x8*)&VT[(t * 16 + m) * KP + c2 * 32 + quad * 8];
                O0[t] = __builtin_amdgcn_mfma_f32_16x16x32_bf16(pa0, vv, O0[t], 0, 0, 0);
                O1[t] = __builtin_amdgcn_mfma_f32_16x16x32_bf16(pa1, vv, O1[t], 0, 0, 0);
            }
        }
    }

    lsum0 += __shfl_xor(lsum0, 16, 64); lsum0 += __shfl_xor(lsum0, 32, 64);
    lsum1 += __shfl_xor(lsum1, 16, 64); lsum1 += __shfl_xor(lsum1, 32, 64);
    if (lane < 16) { lsl[pr0 + lane] = lsum0; lsl[pr1 + lane] = lsum1; }

    __syncthreads();
    for (int s2 = 0; s2 < 16; ++s2) {
        int flat = s2 * 256 + tid;          // flat = d*64 + e
        int d = flat >> 6, e = flat & 63;
        Kb[e * KP + d] = (__bf16)mem[(size_t)h * 4096 + flat];
        VT[e * KP + d] = (__bf16)Gv[(size_t)bh * 4096 + flat];
    }
    __syncthreads();

    __bf16* op = o + ((size_t)bh * N_ + n0) * 64;
    #pragma unroll
    for (int s = 0; s < 2; ++s) {
        const int prs = w * 32 + s * 16;
        bf16x8 ea0, ea1;
        #pragma unroll
        for (int j = 0; j < 8; ++j) {
            ea0[j] = (__bf16)eluf((float)(s == 0 ? qa00[j] : qa10[j]));
            ea1[j] = (__bf16)eluf((float)(s == 0 ? qa01[j] : qa11[j]));
        }
        f32x4 num[4];
        #pragma unroll
        for (int t = 0; t < 4; ++t) {
            bf16x8 b0 = *(const bf16x8*)&Kb[(t * 16 + m) * KP + quad * 8];
            bf16x8 b1 = *(const bf16x8*)&Kb[(t * 16 + m) * KP + 32 + quad * 8];
            f32x4 z = {0.f, 0.f, 0.f, 0.f};
            z = __builtin_amdgcn_mfma_f32_16x16x32_bf16(ea0, b0, z, 0, 0, 0);
            num[t] = __builtin_amdgcn_mfma_f32_16x16x32_bf16(ea1, b1, z, 0, 0, 0);
        }
        *(bf16x8*)&Pw[(prs + m) * KP + quad * 8]      = ea0;
        *(bf16x8*)&Pw[(prs + m) * KP + 32 + quad * 8] = ea1;
        asm volatile("s_waitcnt lgkmcnt(0)" ::: "memory");
        float mq[4][4];
        #pragma unroll
        for (int t = 0; t < 4; ++t)
            #pragma unroll
            for (int r = 0; r < 4; ++r) {
                float eqv = (float)Pw[(prs + quad * 4 + r) * KP + t * 16 + m];
                mq[t][r] = num[t][r] / (eqv * nrm_l[prs + quad * 4 + r]);
            }
        #pragma unroll
        for (int t = 0; t < 4; ++t)
            #pragma unroll
            for (int r = 0; r < 4; ++r)
                Pw[(prs + quad * 4 + r) * KP + t * 16 + m] = (__bf16)mq[t][r];
        asm volatile("s_waitcnt lgkmcnt(0)" ::: "memory");
        bf16x8 ma0 = *(const bf16x8*)&Pw[(prs + m) * KP + quad * 8];
        bf16x8 ma1 = *(const bf16x8*)&Pw[(prs + m) * KP + 32 + quad * 8];

        #pragma unroll
        for (int t = 0; t < 4; ++t) {
            bf16x8 g0 = *(const bf16x8*)&VT[(t * 16 + m) * KP + quad * 8];
            bf16x8 g1 = *(const bf16x8*)&VT[(t * 16 + m) * KP + 32 + quad * 8];
            f32x4 z = {0.f, 0.f, 0.f, 0.f};
            z = __builtin_amdgcn_mfma_f32_16x16x32_bf16(ma0, g0, z, 0, 0, 0);
            f32x4 o2 = __builtin_amdgcn_mfma_f32_16x16x32_bf16(ma1, g1, z, 0, 0, 0);
            #pragma unroll
            for (int r = 0; r < 4; ++r) {
                const int qr = prs + quad * 4 + r;
                float val = ((s == 0) ? O0[t][r] : O1[t][r]) * (gl / lsl[qr])
                            + sigg * o2[r];
                op[(size_t)qr * 64 + t * 16 + m] = (__bf16)val;
            }
        }
    }
}

// ---------------- K5: output projection on MFMA (unchanged) ----------------
__global__ __launch_bounds__(256) void k_outproj(
    const __bf16* __restrict__ o, const float* __restrict__ Wo,
    const float* __restrict__ bo, float* __restrict__ out)
{
    const int row0 = blockIdx.x * 64;      // over B*N
    const int b = row0 >> 11, nb = row0 & 2047;
    __shared__ __align__(16) __bf16 WoS[64 * 40];   // [dout][k] per 32-k block
    const int tid  = threadIdx.x;
    const int w    = tid >> 6, lane = tid & 63;
    const int quad = lane >> 4, m = lane & 15;

    f32x4 acc[4];
    #pragma unroll
    for (int t = 0; t < 4; ++t) { f32x4 z = {0.f, 0.f, 0.f, 0.f}; acc[t] = z; }

    for (int kbk = 0; kbk < 16; ++kbk) {
        for (int s2 = 0; s2 < 8; ++s2) {
            int flat = s2 * 256 + tid;      // flat = n*32 + kk
            int n = flat >> 5, kk = flat & 31;
            WoS[n * 40 + kk] = (__bf16)Wo[(size_t)n * 512 + kbk * 32 + kk];
        }
        __syncthreads();
        const int hc = kbk >> 1;
        size_t arow = (((size_t)b * H_ + hc) * N_ + nb + w * 16 + m);
        bf16x8 af = *(const bf16x8*)&o[arow * 64 + (kbk & 1) * 32 + quad * 8];
        #pragma unroll
        for (int t = 0; t < 4; ++t) {
            bf16x8 bf_ = *(const bf16x8*)&WoS[(t * 16 + m) * 40 + quad * 8];
            acc[t] = __builtin_amdgcn_mfma_f32_16x16x32_bf16(af, bf_, acc[t], 0, 0, 0);
        }
        __syncthreads();
    }
    #pragma unroll
    for (int t = 0; t < 4; ++t) {
        float bias = bo[t * 16 + m];
        #pragma unroll
        for (int r = 0; r < 4; ++r)
            out[(size_t)(row0 + w * 16 + quad * 4 + r) * 64 + t * 16 + m] =
                acc[t][r] + bias;
    }
}

extern "C" void kernel_launch(void* const* d_in, const int* in_sizes, int n_in,
                              void* d_out, int out_size, void* d_ws, size_t ws_size,
                              hipStream_t stream)
{
    const float* q        = (const float*)d_in[0];
    const float* k        = (const float*)d_in[1];
    const float* v        = (const float*)d_in[2];
    const float* Wq       = (const float*)d_in[3];
    const float* Wk       = (const float*)d_in[4];
    const float* Wv       = (const float*)d_in[5];
    const float* Wo       = (const float*)d_in[6];
    const float* bo       = (const float*)d_in[7];
    const float* Wg       = (const float*)d_in[8];
    const float* s_local  = (const float*)d_in[9];
    const float* s_long   = (const float*)d_in[10];
    const float* mem      = (const float*)d_in[11];
    const float* mem_norm = (const float*)d_in[12];

    float* ws = (float*)d_ws;
    float*  kh  = ws;
    __bf16* qb  = (__bf16*)(ws + 4194304);
    __bf16* kb  = (__bf16*)(ws + 6291456);
    __bf16* vb  = (__bf16*)(ws + 8388608);
    __bf16* vbT = (__bf16*)(ws + 10485760);
    float*  Gv  = ws + 12582912;
    float*  pm  = ws + 12713984;
    float*  pg  = ws + 14811136;
    __bf16* o   = (__bf16*)(ws + 12713984);   // aliases pm (dead after k_reduce)

    float* out      = (float*)d_out;
    float* out_mem  = out + 524288;
    float* out_norm = out + 655360;

    k_proj   <<<dim3(128, 8, 3), 256, 0, stream>>>(q, k, v, Wq, Wk, Wv,
                                                   qb, kh, kb, vb, vbT);
    k_memacc <<<dim3(16, 32),    256, 0, stream>>>(kh, vb, mem, mem_norm,
                                                   pm, out_norm);
    k_gv     <<<dim3(16, 32),    256, 0, stream>>>(Wg, vbT, pg);
    k_reduce <<<dim3(512),       256, 0, stream>>>(mem, pm, pg, out_mem, Gv);
    k_flash  <<<dim3(16, 32),    256, 0, stream>>>(qb, kb, vbT, mem, mem_norm, Gv,
                                                   s_local, s_long, o);
    k_outproj<<<dim3(128),       256, 0, stream>>>(o, Wo, bo, out);
}

// Round 12
// 202.902 us; speedup vs baseline: 1.1684x; 1.0028x over previous
//
#include <hip/hip_runtime.h>
#include <math.h>

// InfiniAttention fused forward, MI355X round 12.
// B=4, N=2048, DIM=64, H=8, DH=64.
// Round-12 = round-11 (best: 203.5 us) with ONE k_flash change: the P matrix
// no longer round-trips through LDS. S^T's C-layout (rows=kcol quad*4+r,
// cols=qrow m) IS the A-fragment layout of mfma_f32_16x16x16_bf16
// (A[m][k=quad*4+j]) -- so exp(s) feeds PV directly from registers via
// 4x K=16 MFMAs per k-chunk. Deletes per wave-iter: 8 ds_write_b64 +
// lgkmcnt(0) drain + 4 ds_read_b128 (the mid-loop serialization + ~40% of
// conflicts). V B-frags become b64 reads (same bytes). All else identical.
//
// Workspace (floats, 16908288 total = 67,633,152 B):
//   kh   @ 0         f32  4194304
//   qb   @ 4194304   bf16 [bh][n][d]
//   kb   @ 6291456   bf16 [bh][n][d]  (pre-scaled by 0.1803...)
//   vb   @ 8388608   bf16 [bh][n][d]
//   vbT  @ 10485760  bf16 [bh][e][n]
//   Gv   @ 12582912  f32  131072  [bh][d][e]
//   pm   @ 12713984  f32  2097152 (16 chunks)  <- o bf16 aliases pm
//   pg   @ 14811136  f32  2097152

#define B_   4
#define N_   2048
#define H_   8
#define BH_  32
#define KP   72      // bf16 LDS pitch (144 B)
#define SCLK 0.18033688f   // 0.125 * log2(e), folded into kb

typedef __bf16 bf16x8 __attribute__((ext_vector_type(8)));
typedef __bf16 bf16x4 __attribute__((ext_vector_type(4)));
typedef short  s16x4  __attribute__((ext_vector_type(4)));
typedef float  f32x4  __attribute__((ext_vector_type(4)));

__device__ __forceinline__ float eluf(float x) {
    return x > 0.0f ? x : expm1f(x);   // expm1 critical near 0
}

__device__ __forceinline__ float fexp2(float x) {
    return __builtin_amdgcn_exp2f(x);  // bare v_exp_f32 (inputs in normal range)
}

__device__ __forceinline__ f32x4 mfma16(bf16x4 a, bf16x4 b, f32x4 c) {
#if __has_builtin(__builtin_amdgcn_mfma_f32_16x16x16_bf16)
    return __builtin_amdgcn_mfma_f32_16x16x16_bf16(a, b, c, 0, 0, 0);
#else
    s16x4 ai, bi;
    __builtin_memcpy(&ai, &a, 8);
    __builtin_memcpy(&bi, &b, 8);
    return __builtin_amdgcn_mfma_f32_16x16x16bf16_1k(ai, bi, c, 0, 0, 0);
#endif
}

// ---------------- K2: head projections (unchanged from round-11 PASS) ---------
__global__ __launch_bounds__(256) void k_proj(
    const float* __restrict__ q, const float* __restrict__ k, const float* __restrict__ v,
    const float* __restrict__ Wq, const float* __restrict__ Wk, const float* __restrict__ Wv,
    __bf16* __restrict__ qb, float* __restrict__ kh, __bf16* __restrict__ kb,
    __bf16* __restrict__ vb, __bf16* __restrict__ vbT)
{
    const int which = blockIdx.z;
    const int h    = blockIdx.y;
    const int row0 = blockIdx.x * 64;   // over B*N = 8192
    const int tid  = threadIdx.x;
    const int b = row0 >> 11, nb = row0 & 2047;

    __shared__ __align__(16) float  AsT[64][68];   // [dim][row] (q/k path)
    __shared__ __align__(16) float  WsT[64][68];   // [dim][col] (q/k path)
    __shared__ __align__(16) __bf16 Cs[64 * 72];   // C bounce (v path)

    if (which == 2) {
        // ---- v: bf16 MFMA ----
        const int w = tid >> 6, lane = tid & 63;
        const int quad = lane >> 4, m = lane & 15;
        const float* ar = v + (size_t)(row0 + w * 16 + m) * 64;
        bf16x8 a0, a1;
        #pragma unroll
        for (int j = 0; j < 8; ++j) {
            a0[j] = (__bf16)ar[quad * 8 + j];
            a1[j] = (__bf16)ar[32 + quad * 8 + j];
        }
        f32x4 acc[4];
        #pragma unroll
        for (int t = 0; t < 4; ++t) {
            const float* wr = Wv + (size_t)(h * 64 + t * 16 + m) * 64;
            bf16x8 b0, b1;
            #pragma unroll
            for (int j = 0; j < 8; ++j) {
                b0[j] = (__bf16)wr[quad * 8 + j];
                b1[j] = (__bf16)wr[32 + quad * 8 + j];
            }
            f32x4 z = {0.f, 0.f, 0.f, 0.f};
            z = __builtin_amdgcn_mfma_f32_16x16x32_bf16(a0, b0, z, 0, 0, 0);
            acc[t] = __builtin_amdgcn_mfma_f32_16x16x32_bf16(a1, b1, z, 0, 0, 0);
        }
        #pragma unroll
        for (int t = 0; t < 4; ++t)
            #pragma unroll
            for (int r = 0; r < 4; ++r)
                Cs[(w * 16 + quad * 4 + r) * 72 + t * 16 + m] = (__bf16)acc[t][r];
        __syncthreads();
        // row-major -> vb
        const int rr = tid >> 2, csg = (tid & 3) * 16;
        bf16x8 r0 = *(const bf16x8*)&Cs[rr * 72 + csg];
        bf16x8 r1 = *(const bf16x8*)&Cs[rr * 72 + csg + 8];
        size_t gb = ((((size_t)b * H_ + h) * N_ + nb + rr) << 6) + csg;
        *(bf16x8*)&vb[gb]     = r0;
        *(bf16x8*)&vb[gb + 8] = r1;
        // col-major -> vbT
        const int e = tid >> 2, ns = (tid & 3) * 16;
        bf16x8 t0, t1;
        #pragma unroll
        for (int j = 0; j < 8; ++j) {
            t0[j] = Cs[(ns + j) * 72 + e];
            t1[j] = Cs[(ns + 8 + j) * 72 + e];
        }
        size_t base = (((size_t)b * H_ + h) * 64 + e) * (size_t)N_ + nb + ns;
        *(bf16x8*)&vbT[base]     = t0;
        *(bf16x8*)&vbT[base + 8] = t1;
        return;
    }

    // ---- q / k: exact f32 chain (byte-identical math to round-2..11 PASS) ----
    const float* __restrict__ src = (which == 0) ? q : k;
    const float* __restrict__ W   = (which == 0) ? Wq : Wk;
    for (int s = 0; s < 16; ++s) {
        int flat = s * 256 + tid;
        int r = flat >> 6, d = flat & 63;
        AsT[d][r] = src[(size_t)(row0 + r) * 64 + d];
        WsT[d][r] = W[(size_t)(h * 64 + r) * 64 + d];
    }
    __syncthreads();

    const int ty = tid >> 4, tx = tid & 15;
    float acc[4][4];
    #pragma unroll
    for (int i = 0; i < 4; ++i)
        #pragma unroll
        for (int j = 0; j < 4; ++j) acc[i][j] = 0.0f;
    for (int kd = 0; kd < 64; ++kd) {
        float4 a4 = *(const float4*)&AsT[kd][ty * 4];
        float4 w4 = *(const float4*)&WsT[kd][tx * 4];
        float a[4] = {a4.x, a4.y, a4.z, a4.w};
        float w[4] = {w4.x, w4.y, w4.z, w4.w};
        #pragma unroll
        for (int i = 0; i < 4; ++i)
            #pragma unroll
            for (int j = 0; j < 4; ++j) acc[i][j] = fmaf(a[i], w[j], acc[i][j]);
    }

    if (which == 0) {
        #pragma unroll
        for (int i = 0; i < 4; ++i) {
            size_t idx = ((((size_t)b * H_ + h) * N_ + nb + ty * 4 + i) << 6) + tx * 4;
            bf16x4 o4 = {(__bf16)acc[i][0], (__bf16)acc[i][1],
                         (__bf16)acc[i][2], (__bf16)acc[i][3]};
            *(bf16x4*)&qb[idx] = o4;
        }
    } else {
        #pragma unroll
        for (int i = 0; i < 4; ++i) {
            size_t idx = ((((size_t)b * H_ + h) * N_ + nb + ty * 4 + i) << 6) + tx * 4;
            *(float4*)&kh[idx] = make_float4(acc[i][0], acc[i][1], acc[i][2], acc[i][3]);
            bf16x4 o4 = {(__bf16)(acc[i][0] * SCLK), (__bf16)(acc[i][1] * SCLK),
                         (__bf16)(acc[i][2] * SCLK), (__bf16)(acc[i][3] * SCLK)};
            *(bf16x4*)&kb[idx] = o4;
        }
    }
}

// ---- K3: memory-update on split-bf16 MFMA (unchanged from round-11 PASS) ----
__global__ __launch_bounds__(256) void k_memacc(
    const float* __restrict__ kh, const __bf16* __restrict__ vb,
    const float* __restrict__ mem, const float* __restrict__ mem_norm,
    float* __restrict__ pmem, float* __restrict__ out_norm)
{
    const int chunk = blockIdx.x;    // 0..15
    const int bh    = blockIdx.y;
    const int h     = bh & 7;
    const int n0    = chunk * 128;

    __shared__ __align__(16) __bf16 memT_hi[64 * KP], memT_lo[64 * KP]; // [e][d]
    __shared__ __align__(16) __bf16 ekn_hi[64 * KP],  ekn_lo[64 * KP];  // [n][d]
    __shared__ __align__(16) __bf16 ekT_hi[64 * KP],  ekT_lo[64 * KP];  // [d][n]
    __shared__ __align__(16) __bf16 vtT_hi[64 * KP],  vtT_lo[64 * KP];  // [e][n]

    const int tid  = threadIdx.x;
    const int w    = tid >> 6, lane = tid & 63;
    const int quad = lane >> 4, m = lane & 15;

    for (int s = 0; s < 16; ++s) {
        int flat = s * 256 + tid;          // flat = d*64 + e
        int d = flat >> 6, e = flat & 63;
        float mv = mem[(size_t)h * 4096 + flat];
        __bf16 hi = (__bf16)mv;
        memT_hi[e * KP + d] = hi;
        memT_lo[e * KP + d] = (__bf16)(mv - (float)hi);
    }

    bf16x8 onesv;
    #pragma unroll
    for (int j = 0; j < 8; ++j) onesv[j] = (m == 0) ? (__bf16)1.0f : (__bf16)0.0f;

    f32x4 accM[4];
    #pragma unroll
    for (int t = 0; t < 4; ++t) { f32x4 z = {0.f, 0.f, 0.f, 0.f}; accM[t] = z; }
    __syncthreads();

    for (int sub = 0; sub < 2; ++sub) {
        const int nb = n0 + sub * 64;
        // ---- A1: ek exact f32, split hi/lo into natural + transposed ----
        for (int rr = w; rr < 64; rr += 4) {
            const int n = nb + rr;
            float ekv = eluf(kh[((size_t)bh * N_ + n) * 64 + lane]);
            __bf16 hi = (__bf16)ekv;
            __bf16 lo = (__bf16)(ekv - (float)hi);
            ekn_hi[rr * KP + lane] = hi;
            ekn_lo[rr * KP + lane] = lo;
            ekT_hi[lane * KP + rr] = hi;
            ekT_lo[lane * KP + rr] = lo;
        }
        __syncthreads();

        // ---- A2: km = ek@mem (3-pass) + out_norm (ones column) ----
        f32x4 km[4];
        #pragma unroll
        for (int t = 0; t < 4; ++t) { f32x4 z = {0.f, 0.f, 0.f, 0.f}; km[t] = z; }
        f32x4 nsum = {0.f, 0.f, 0.f, 0.f};
        #pragma unroll
        for (int c2 = 0; c2 < 2; ++c2) {
            bf16x8 Ah = *(const bf16x8*)&ekn_hi[(w * 16 + m) * KP + c2 * 32 + quad * 8];
            bf16x8 Al = *(const bf16x8*)&ekn_lo[(w * 16 + m) * KP + c2 * 32 + quad * 8];
            nsum = __builtin_amdgcn_mfma_f32_16x16x32_bf16(Ah, onesv, nsum, 0, 0, 0);
            nsum = __builtin_amdgcn_mfma_f32_16x16x32_bf16(Al, onesv, nsum, 0, 0, 0);
            #pragma unroll
            for (int et = 0; et < 4; ++et) {
                bf16x8 Bh = *(const bf16x8*)&memT_hi[(et * 16 + m) * KP + c2 * 32 + quad * 8];
                bf16x8 Bl = *(const bf16x8*)&memT_lo[(et * 16 + m) * KP + c2 * 32 + quad * 8];
                km[et] = __builtin_amdgcn_mfma_f32_16x16x32_bf16(Al, Bh, km[et], 0, 0, 0);
                km[et] = __builtin_amdgcn_mfma_f32_16x16x32_bf16(Ah, Bl, km[et], 0, 0, 0);
                km[et] = __builtin_amdgcn_mfma_f32_16x16x32_bf16(Ah, Bh, km[et], 0, 0, 0);
            }
        }
        if (m == 0) {
            #pragma unroll
            for (int r = 0; r < 4; ++r)
                out_norm[(size_t)bh * N_ + nb + w * 16 + quad * 4 + r] = nsum[r];
        }
        float nrmv[4];
        #pragma unroll
        for (int r = 0; r < 4; ++r)
            nrmv[r] = mem_norm[(size_t)h * N_ + nb + w * 16 + quad * 4 + r];
        #pragma unroll
        for (int et = 0; et < 4; ++et) {
            #pragma unroll
            for (int r = 0; r < 4; ++r) {
                const int nl = w * 16 + quad * 4 + r;
                const int e  = et * 16 + m;
                float vh  = (float)vb[((size_t)bh * N_ + nb + nl) * 64 + e];
                float ekv = (float)ekn_hi[nl * KP + e] + (float)ekn_lo[nl * KP + e];
                float vt  = vh - km[et][r] * __builtin_amdgcn_rcpf(ekv * nrmv[r]);
                __bf16 hi = (__bf16)vt;
                vtT_hi[e * KP + nl] = hi;
                vtT_lo[e * KP + nl] = (__bf16)(vt - (float)hi);
            }
        }
        __syncthreads();

        // ---- B: accM += ek^T @ v_term (3-pass MFMA) ----
        #pragma unroll
        for (int c2 = 0; c2 < 2; ++c2) {
            bf16x8 Ah = *(const bf16x8*)&ekT_hi[(w * 16 + m) * KP + c2 * 32 + quad * 8];
            bf16x8 Al = *(const bf16x8*)&ekT_lo[(w * 16 + m) * KP + c2 * 32 + quad * 8];
            #pragma unroll
            for (int et = 0; et < 4; ++et) {
                bf16x8 Bh = *(const bf16x8*)&vtT_hi[(et * 16 + m) * KP + c2 * 32 + quad * 8];
                bf16x8 Bl = *(const bf16x8*)&vtT_lo[(et * 16 + m) * KP + c2 * 32 + quad * 8];
                accM[et] = __builtin_amdgcn_mfma_f32_16x16x32_bf16(Al, Bh, accM[et], 0, 0, 0);
                accM[et] = __builtin_amdgcn_mfma_f32_16x16x32_bf16(Ah, Bl, accM[et], 0, 0, 0);
                accM[et] = __builtin_amdgcn_mfma_f32_16x16x32_bf16(Ah, Bh, accM[et], 0, 0, 0);
            }
        }
        __syncthreads();
    }

    const size_t base = ((size_t)chunk * BH_ + bh) * 4096;
    #pragma unroll
    for (int et = 0; et < 4; ++et)
        #pragma unroll
        for (int r = 0; r < 4; ++r)
            pmem[base + (size_t)(w * 16 + quad * 4 + r) * 64 + et * 16 + m] =
                accM[et][r];
}

// ---- K3g: Gv partials = Wg^T @ vh (unchanged from round-6 PASS) ----
__global__ __launch_bounds__(256) void k_gv(
    const float* __restrict__ Wg, const __bf16* __restrict__ vbT,
    float* __restrict__ pGv)
{
    const int chunk = blockIdx.x;    // 0..15
    const int bh    = blockIdx.y;
    const int n0    = chunk * 128;
    __shared__ __align__(16) __bf16 WgT[64 * 136];   // [d][n], pitch 272B
    const int tid  = threadIdx.x;
    const int w    = tid >> 6, lane = tid & 63;
    const int quad = lane >> 4, m = tid & 15;

    for (int s = 0; s < 8; ++s) {
        int f4 = s * 256 + tid;
        int n = f4 >> 4, dg = (f4 & 15) * 4;
        float4 wv = *(const float4*)&Wg[(size_t)(n0 + n) * 64 + dg];
        WgT[(dg + 0) * 136 + n] = (__bf16)wv.x;
        WgT[(dg + 1) * 136 + n] = (__bf16)wv.y;
        WgT[(dg + 2) * 136 + n] = (__bf16)wv.z;
        WgT[(dg + 3) * 136 + n] = (__bf16)wv.w;
    }
    __syncthreads();

    f32x4 acc[4];
    #pragma unroll
    for (int t = 0; t < 4; ++t) { f32x4 z = {0.f, 0.f, 0.f, 0.f}; acc[t] = z; }
    #pragma unroll
    for (int c = 0; c < 4; ++c) {
        bf16x8 Af = *(const bf16x8*)&WgT[(w * 16 + m) * 136 + c * 32 + quad * 8];
        #pragma unroll
        for (int et = 0; et < 4; ++et) {
            bf16x8 Bf = *(const bf16x8*)&vbT[((size_t)bh * 64 + et * 16 + m) * N_ +
                                             n0 + c * 32 + quad * 8];
            acc[et] = __builtin_amdgcn_mfma_f32_16x16x32_bf16(Af, Bf, acc[et], 0, 0, 0);
        }
    }
    const size_t base = ((size_t)chunk * BH_ + bh) * 4096;
    #pragma unroll
    for (int et = 0; et < 4; ++et)
        #pragma unroll
        for (int r = 0; r < 4; ++r)
            pGv[base + (size_t)(w * 16 + quad * 4 + r) * 64 + et * 16 + m] =
                acc[et][r];
}

// ---------------- K3b: reduce partials (unchanged) ----------------
__global__ __launch_bounds__(256) void k_reduce(
    const float* __restrict__ mem, const float* __restrict__ pmem,
    const float* __restrict__ pGv, float* __restrict__ out_mem, float* __restrict__ Gv)
{
    const int idx = blockIdx.x * 256 + threadIdx.x;
    const int bh = idx >> 12, h = bh & 7, de = idx & 4095;
    float sm = mem[(size_t)h * 4096 + de];
    float sg = 0.0f;
    #pragma unroll
    for (int c = 0; c < 16; ++c) {
        sm += pmem[(size_t)c * 131072 + idx];
        sg += pGv[(size_t)c * 131072 + idx];
    }
    out_mem[idx] = sm;
    Gv[idx] = sg;
}

// ---------- K4: flash attention (P stays in registers via K=16 MFMA) ----------
// 256 thr = 4 waves; 128-row blocks; wave owns 32 q-rows (2 strips).
__global__ __launch_bounds__(256, 4) void k_flash(
    const __bf16* __restrict__ qb, const __bf16* __restrict__ kb,
    const __bf16* __restrict__ vbT, const float* __restrict__ mem,
    const float* __restrict__ mem_norm, const float* __restrict__ Gv,
    const float* __restrict__ s_local_p, const float* __restrict__ s_long_p,
    __bf16* __restrict__ o)
{
    const int n0 = blockIdx.x * 128;
    const int bh = blockIdx.y;
    const int h  = bh & 7;
    const __bf16* __restrict__ kbp = kb  + (size_t)bh * N_ * 64;
    const __bf16* __restrict__ vtp = vbT + (size_t)bh * 64 * N_;

    __shared__ __align__(16) __bf16 Kb[64 * KP];    // [kcol][d]; epilogue: MT [e][d]
    __shared__ __align__(16) __bf16 VT[64 * KP];    // [e][n];   epilogue: GT [e][d]
    __shared__ __align__(16) __bf16 Pw[128 * KP];   // epilogue strips only
    __shared__ float lsl[128];
    __shared__ float nrm_l[128];

    const int tid  = threadIdx.x;
    const int w    = tid >> 6, lane = tid & 63;
    const int quad = lane >> 4, m = lane & 15;
    const float gl   = 1.0f - 1.0f / (1.0f + __expf(-s_local_p[0]));
    const float sigg = 1.0f / (1.0f + __expf(-s_long_p[0]));

    if (tid < 128) nrm_l[tid] = mem_norm[(size_t)h * N_ + n0 + tid];

    const size_t q0 = ((size_t)bh * N_ + n0 + w * 32 + m) * 64;
    const size_t q1 = q0 + 16 * 64;
    bf16x8 qa00 = *(const bf16x8*)&qb[q0 + quad * 8];
    bf16x8 qa01 = *(const bf16x8*)&qb[q0 + 32 + quad * 8];
    bf16x8 qa10 = *(const bf16x8*)&qb[q1 + quad * 8];
    bf16x8 qa11 = *(const bf16x8*)&qb[q1 + 32 + quad * 8];

    f32x4 O0[4], O1[4];
    #pragma unroll
    for (int t = 0; t < 4; ++t) {
        f32x4 z = {0.f, 0.f, 0.f, 0.f};
        O0[t] = z; O1[t] = z;
    }
    float lsum0 = 0.f, lsum1 = 0.f;
    const int pr0 = w * 32, pr1 = w * 32 + 16;

    const int srow = tid >> 2, scg = (tid & 3) * 16;
    bf16x8 pk0 = *(const bf16x8*)&kbp[(size_t)srow * 64 + scg];
    bf16x8 pk1 = *(const bf16x8*)&kbp[(size_t)srow * 64 + scg + 8];
    bf16x8 pv0 = *(const bf16x8*)&vtp[(size_t)srow * N_ + scg];
    bf16x8 pv1 = *(const bf16x8*)&vtp[(size_t)srow * N_ + scg + 8];

    for (int c = 0; c < 32; ++c) {
        __syncthreads();
        *(bf16x8*)&Kb[srow * KP + scg]     = pk0;
        *(bf16x8*)&Kb[srow * KP + scg + 8] = pk1;
        *(bf16x8*)&VT[srow * KP + scg]     = pv0;
        *(bf16x8*)&VT[srow * KP + scg + 8] = pv1;
        __syncthreads();
        if (c + 1 < 32) {
            const size_t kn = (size_t)((c + 1) * 64 + srow) * 64 + scg;
            const size_t vn = (size_t)srow * N_ + (c + 1) * 64 + scg;
            pk0 = *(const bf16x8*)&kbp[kn];
            pk1 = *(const bf16x8*)&kbp[kn + 8];
            pv0 = *(const bf16x8*)&vtp[vn];
            pv1 = *(const bf16x8*)&vtp[vn + 8];
        }

        // ---- S^T = K' Q^T (K pre-scaled by 0.125*log2e) ----
        f32x4 s0[4], s1[4];
        #pragma unroll
        for (int t = 0; t < 4; ++t) {
            bf16x8 ka0 = *(const bf16x8*)&Kb[(t * 16 + m) * KP + quad * 8];
            bf16x8 ka1 = *(const bf16x8*)&Kb[(t * 16 + m) * KP + 32 + quad * 8];
            f32x4 z = {0.f, 0.f, 0.f, 0.f};
            z = __builtin_amdgcn_mfma_f32_16x16x32_bf16(ka0, qa00, z, 0, 0, 0);
            s0[t] = __builtin_amdgcn_mfma_f32_16x16x32_bf16(ka1, qa01, z, 0, 0, 0);
            f32x4 z2 = {0.f, 0.f, 0.f, 0.f};
            z2 = __builtin_amdgcn_mfma_f32_16x16x32_bf16(ka0, qa10, z2, 0, 0, 0);
            s1[t] = __builtin_amdgcn_mfma_f32_16x16x32_bf16(ka1, qa11, z2, 0, 0, 0);
        }

        // ---- p = v_exp_f32(s); lsum; P A-frags stay in REGISTERS ----
        // C-layout of s0[t]: value for qrow=m, kcol = t*16 + quad*4 + r.
        // That is exactly the A-fragment of mfma_f32_16x16x16_bf16
        // (A[m][k=quad*4+j]) for the K=16 chunk at kcol base t*16.
        bf16x4 pa0[4], pa1[4];
        #pragma unroll
        for (int t = 0; t < 4; ++t) {
            float p0 = fexp2(s0[t][0]), p1 = fexp2(s0[t][1]);
            float p2 = fexp2(s0[t][2]), p3 = fexp2(s0[t][3]);
            lsum0 += p0 + p1 + p2 + p3;
            bf16x4 pk = {(__bf16)p0, (__bf16)p1, (__bf16)p2, (__bf16)p3};
            pa0[t] = pk;
            float r0 = fexp2(s1[t][0]), r1 = fexp2(s1[t][1]);
            float r2 = fexp2(s1[t][2]), r3 = fexp2(s1[t][3]);
            lsum1 += r0 + r1 + r2 + r3;
            bf16x4 rk = {(__bf16)r0, (__bf16)r1, (__bf16)r2, (__bf16)r3};
            pa1[t] = rk;
        }

        // ---- O += P V via K=16 MFMAs; V B-frag: B[k=quad*4+j][n=m] ----
        #pragma unroll
        for (int t = 0; t < 4; ++t) {
            #pragma unroll
            for (int et = 0; et < 4; ++et) {
                bf16x4 vb4 = *(const bf16x4*)&VT[(et * 16 + m) * KP + t * 16 + quad * 4];
                O0[et] = mfma16(pa0[t], vb4, O0[et]);
                O1[et] = mfma16(pa1[t], vb4, O1[et]);
            }
        }
    }

    lsum0 += __shfl_xor(lsum0, 16, 64); lsum0 += __shfl_xor(lsum0, 32, 64);
    lsum1 += __shfl_xor(lsum1, 16, 64); lsum1 += __shfl_xor(lsum1, 32, 64);
    if (lane < 16) { lsl[pr0 + lane] = lsum0; lsl[pr1 + lane] = lsum1; }

    __syncthreads();
    for (int s2 = 0; s2 < 16; ++s2) {
        int flat = s2 * 256 + tid;          // flat = d*64 + e
        int d = flat >> 6, e = flat & 63;
        Kb[e * KP + d] = (__bf16)mem[(size_t)h * 4096 + flat];
        VT[e * KP + d] = (__bf16)Gv[(size_t)bh * 4096 + flat];
    }
    __syncthreads();

    __bf16* op = o + ((size_t)bh * N_ + n0) * 64;
    #pragma unroll
    for (int s = 0; s < 2; ++s) {
        const int prs = w * 32 + s * 16;
        bf16x8 ea0, ea1;
        #pragma unroll
        for (int j = 0; j < 8; ++j) {
            ea0[j] = (__bf16)eluf((float)(s == 0 ? qa00[j] : qa10[j]));
            ea1[j] = (__bf16)eluf((float)(s == 0 ? qa01[j] : qa11[j]));
        }
        f32x4 num[4];
        #pragma unroll
        for (int t = 0; t < 4; ++t) {
            bf16x8 b0 = *(const bf16x8*)&Kb[(t * 16 + m) * KP + quad * 8];
            bf16x8 b1 = *(const bf16x8*)&Kb[(t * 16 + m) * KP + 32 + quad * 8];
            f32x4 z = {0.f, 0.f, 0.f, 0.f};
            z = __builtin_amdgcn_mfma_f32_16x16x32_bf16(ea0, b0, z, 0, 0, 0);
            num[t] = __builtin_amdgcn_mfma_f32_16x16x32_bf16(ea1, b1, z, 0, 0, 0);
        }
        *(bf16x8*)&Pw[(prs + m) * KP + quad * 8]      = ea0;
        *(bf16x8*)&Pw[(prs + m) * KP + 32 + quad * 8] = ea1;
        asm volatile("s_waitcnt lgkmcnt(0)" ::: "memory");
        float mq[4][4];
        #pragma unroll
        for (int t = 0; t < 4; ++t)
            #pragma unroll
            for (int r = 0; r < 4; ++r) {
                float eqv = (float)Pw[(prs + quad * 4 + r) * KP + t * 16 + m];
                mq[t][r] = num[t][r] / (eqv * nrm_l[prs + quad * 4 + r]);
            }
        #pragma unroll
        for (int t = 0; t < 4; ++t)
            #pragma unroll
            for (int r = 0; r < 4; ++r)
                Pw[(prs + quad * 4 + r) * KP + t * 16 + m] = (__bf16)mq[t][r];
        asm volatile("s_waitcnt lgkmcnt(0)" ::: "memory");
        bf16x8 ma0 = *(const bf16x8*)&Pw[(prs + m) * KP + quad * 8];
        bf16x8 ma1 = *(const bf16x8*)&Pw[(prs + m) * KP + 32 + quad * 8];

        #pragma unroll
        for (int t = 0; t < 4; ++t) {
            bf16x8 g0 = *(const bf16x8*)&VT[(t * 16 + m) * KP + quad * 8];
            bf16x8 g1 = *(const bf16x8*)&VT[(t * 16 + m) * KP + 32 + quad * 8];
            f32x4 z = {0.f, 0.f, 0.f, 0.f};
            z = __builtin_amdgcn_mfma_f32_16x16x32_bf16(ma0, g0, z, 0, 0, 0);
            f32x4 o2 = __builtin_amdgcn_mfma_f32_16x16x32_bf16(ma1, g1, z, 0, 0, 0);
            #pragma unroll
            for (int r = 0; r < 4; ++r) {
                const int qr = prs + quad * 4 + r;
                float val = ((s == 0) ? O0[t][r] : O1[t][r]) * (gl / lsl[qr])
                            + sigg * o2[r];
                op[(size_t)qr * 64 + t * 16 + m] = (__bf16)val;
            }
        }
    }
}

// ---------------- K5: output projection on MFMA (unchanged) ----------------
__global__ __launch_bounds__(256) void k_outproj(
    const __bf16* __restrict__ o, const float* __restrict__ Wo,
    const float* __restrict__ bo, float* __restrict__ out)
{
    const int row0 = blockIdx.x * 64;      // over B*N
    const int b = row0 >> 11, nb = row0 & 2047;
    __shared__ __align__(16) __bf16 WoS[64 * 40];   // [dout][k] per 32-k block
    const int tid  = threadIdx.x;
    const int w    = tid >> 6, lane = tid & 63;
    const int quad = lane >> 4, m = lane & 15;

    f32x4 acc[4];
    #pragma unroll
    for (int t = 0; t < 4; ++t) { f32x4 z = {0.f, 0.f, 0.f, 0.f}; acc[t] = z; }

    for (int kbk = 0; kbk < 16; ++kbk) {
        for (int s2 = 0; s2 < 8; ++s2) {
            int flat = s2 * 256 + tid;      // flat = n*32 + kk
            int n = flat >> 5, kk = flat & 31;
            WoS[n * 40 + kk] = (__bf16)Wo[(size_t)n * 512 + kbk * 32 + kk];
        }
        __syncthreads();
        const int hc = kbk >> 1;
        size_t arow = (((size_t)b * H_ + hc) * N_ + nb + w * 16 + m);
        bf16x8 af = *(const bf16x8*)&o[arow * 64 + (kbk & 1) * 32 + quad * 8];
        #pragma unroll
        for (int t = 0; t < 4; ++t) {
            bf16x8 bf_ = *(const bf16x8*)&WoS[(t * 16 + m) * 40 + quad * 8];
            acc[t] = __builtin_amdgcn_mfma_f32_16x16x32_bf16(af, bf_, acc[t], 0, 0, 0);
        }
        __syncthreads();
    }
    #pragma unroll
    for (int t = 0; t < 4; ++t) {
        float bias = bo[t * 16 + m];
        #pragma unroll
        for (int r = 0; r < 4; ++r)
            out[(size_t)(row0 + w * 16 + quad * 4 + r) * 64 + t * 16 + m] =
                acc[t][r] + bias;
    }
}

extern "C" void kernel_launch(void* const* d_in, const int* in_sizes, int n_in,
                              void* d_out, int out_size, void* d_ws, size_t ws_size,
                              hipStream_t stream)
{
    const float* q        = (const float*)d_in[0];
    const float* k        = (const float*)d_in[1];
    const float* v        = (const float*)d_in[2];
    const float* Wq       = (const float*)d_in[3];
    const float* Wk       = (const float*)d_in[4];
    const float* Wv       = (const float*)d_in[5];
    const float* Wo       = (const float*)d_in[6];
    const float* bo       = (const float*)d_in[7];
    const float* Wg       = (const float*)d_in[8];
    const float* s_local  = (const float*)d_in[9];
    const float* s_long   = (const float*)d_in[10];
    const float* mem      = (const float*)d_in[11];
    const float* mem_norm = (const float*)d_in[12];

    float* ws = (float*)d_ws;
    float*  kh  = ws;
    __bf16* qb  = (__bf16*)(ws + 4194304);
    __bf16* kb  = (__bf16*)(ws + 6291456);
    __bf16* vb  = (__bf16*)(ws + 8388608);
    __bf16* vbT = (__bf16*)(ws + 10485760);
    float*  Gv  = ws + 12582912;
    float*  pm  = ws + 12713984;
    float*  pg  = ws + 14811136;
    __bf16* o   = (__bf16*)(ws + 12713984);   // aliases pm (dead after k_reduce)

    float* out      = (float*)d_out;
    float* out_mem  = out + 524288;
    float* out_norm = out + 655360;

    k_proj   <<<dim3(128, 8, 3), 256, 0, stream>>>(q, k, v, Wq, Wk, Wv,
                                                   qb, kh, kb, vb, vbT);
    k_memacc <<<dim3(16, 32),    256, 0, stream>>>(kh, vb, mem, mem_norm,
                                                   pm, out_norm);
    k_gv     <<<dim3(16, 32),    256, 0, stream>>>(Wg, vbT, pg);
    k_reduce <<<dim3(512),       256, 0, stream>>>(mem, pm, pg, out_mem, Gv);
    k_flash  <<<dim3(16, 32),    256, 0, stream>>>(qb, kb, vbT, mem, mem_norm, Gv,
                                                   s_local, s_long, o);
    k_outproj<<<dim3(128),       256, 0, stream>>>(o, Wo, bo, out);
}